// Round 1
// 537.936 us; speedup vs baseline: 1.1636x; 1.1636x over previous
//
#include <hip/hip_runtime.h>
#include <math.h>

namespace {
constexpr int BN = 64;
constexpr int HW = 1024;
constexpr int NS = BN*8*HW;      // 524288

constexpr float C2f = 0.2f, C3f = 0.3f, C4f = 0.8f, C5f = (float)(8.0/9.0);
constexpr float A21 = 0.2f;
constexpr float A31 = (float)(3.0/40.0),  A32 = (float)(9.0/40.0);
constexpr float A41 = (float)(44.0/45.0), A42 = (float)(-56.0/15.0), A43 = (float)(32.0/9.0);
constexpr float A51 = (float)(19372.0/6561.0), A52 = (float)(-25360.0/2187.0),
                A53 = (float)(64448.0/6561.0), A54 = (float)(-212.0/729.0);
constexpr float A61 = (float)(9017.0/3168.0), A62 = (float)(-355.0/33.0),
                A63 = (float)(46732.0/5247.0), A64 = (float)(49.0/176.0),
                A65 = (float)(-5103.0/18656.0);
constexpr float B1c = (float)(35.0/384.0), B3c = (float)(500.0/1113.0),
                B4c = (float)(125.0/192.0), B5c = (float)(-2187.0/6784.0),
                B6c = (float)(11.0/84.0);
constexpr float E1c = (float)(71.0/57600.0), E3c = (float)(-71.0/16695.0),
                E4c = (float)(71.0/1920.0), E5c = (float)(-17253.0/339200.0),
                E6c = (float)(22.0/525.0),  E7c = (float)(-1.0/40.0);
constexpr float RTOL = 1e-3f, ATOL = 1e-3f;

// ws layout (floats / ints)
constexpr size_t OFF_PART = 0;        // 1024 floats (double-buffered by step parity)
constexpr size_t OFF_FLAG = 1024;     // 512 ints
constexpr size_t OFF_CNT  = 1536;     // 1 int (+pad) [unused now, kept]
constexpr size_t OFF_TSUM = 1600;     // 576
constexpr size_t OFF_W2P  = 2176;     // 36864 halfs = 18432 floats
constexpr size_t OFF_Y    = 20608;    // y buffers px-major: [b][px][8]
constexpr size_t OFF_Y5   = OFF_Y  + (size_t)NS;
constexpr size_t OFF_K    = OFF_Y5 + (size_t)NS;   // 7*NS (k1..k7, px-major)
constexpr size_t OFF_WPK  = OFF_K + (size_t)7*NS;  // w1t(512) w10(64) w3t(512) w30(8)
}

__constant__ float g_cf[6][5] = {
    {A21, 0, 0, 0, 0},
    {A31, A32, 0, 0, 0},
    {A41, A42, A43, 0, 0},
    {A51, A52, A53, A54, 0},
    {A61, A62, A63, A64, A65},
    {0, 0, 0, 0, 0}};
__constant__ float g_ct[6] = {C2f, C3f, C4f, C5f, 1.0f, 1.0f};

typedef _Float16 hfrag8 __attribute__((ext_vector_type(8)));
typedef float f32x16 __attribute__((ext_vector_type(16)));

// ---- system-scope (L3-coherent) accessors ----
__device__ __forceinline__ float ld_sysf(const float* p) {
    return __hip_atomic_load(p, __ATOMIC_RELAXED, __HIP_MEMORY_SCOPE_SYSTEM);
}
__device__ __forceinline__ float2 ld_sysf2(const float* p) {
    union { unsigned long long u; float2 f; } c;
    c.u = __hip_atomic_load((const unsigned long long*)p, __ATOMIC_RELAXED,
                            __HIP_MEMORY_SCOPE_SYSTEM);
    return c.f;
}
__device__ __forceinline__ void st_sysf(float* p, float v) {
    __hip_atomic_store(p, v, __ATOMIC_RELAXED, __HIP_MEMORY_SCOPE_SYSTEM);
}
__device__ __forceinline__ void st_sysf2(float* p, float a, float b) {
    union { unsigned long long u; float2 f; } c;
    c.f = make_float2(a, b);
    __hip_atomic_store((unsigned long long*)p, c.u, __ATOMIC_RELAXED,
                       __HIP_MEMORY_SCOPE_SYSTEM);
}

// 8-float load/store with scope selected by row class (sys = boundary row)
__device__ __forceinline__ void ld8(const float* p, float* v, bool sys) {
    if (sys) {
        #pragma unroll
        for (int h = 0; h < 4; h++) {
            float2 t = ld_sysf2(p + 2*h);
            v[2*h] = t.x; v[2*h+1] = t.y;
        }
    } else {
        float4 a = *(const float4*)p;
        float4 b = *(const float4*)(p + 4);
        v[0]=a.x; v[1]=a.y; v[2]=a.z; v[3]=a.w;
        v[4]=b.x; v[5]=b.y; v[6]=b.z; v[7]=b.w;
    }
}
__device__ __forceinline__ void st8(float* p, const float* v, bool sys) {
    if (sys) {
        st_sysf2(p,     v[0], v[1]);
        st_sysf2(p + 2, v[2], v[3]);
        st_sysf2(p + 4, v[4], v[5]);
        st_sysf2(p + 6, v[6], v[7]);
    } else {
        *(float4*)p       = make_float4(v[0], v[1], v[2], v[3]);
        *(float4*)(p + 4) = make_float4(v[4], v[5], v[6], v[7]);
    }
}

// ---------------- init: y0 (px-major) = concat(x, zeros); zero sync state ----------------
__global__ __launch_bounds__(256)
void k_init(const float* __restrict__ x, float* __restrict__ y,
            int* __restrict__ flags, unsigned* __restrict__ cnt)
{
    int idx = blockIdx.x*256 + threadIdx.x;           // < NS
    int b = idx >> 13, px = (idx >> 3) & 1023, c = idx & 7;
    y[idx] = (c < 3) ? x[(size_t)(b*3 + c)*1024 + px] : 0.0f;
    if (idx < 512) flags[idx] = 0;
    if (idx == 600) *cnt = 0u;
}

// ---------------- prepack: w2 fp16 frag order + t-channel table + w1/w3 transposes ----------------
__global__ __launch_bounds__(256)
void k_prepack(const float* __restrict__ w1, const float* __restrict__ w2,
               const float* __restrict__ w3, _Float16* __restrict__ w2p,
               float* __restrict__ tsum, float* __restrict__ wpk)
{
    int gid = blockIdx.x*256 + threadIdx.x;
    if (gid < 36864) {
        int j    = gid & 7;
        int lane = (gid >> 3) & 63;
        int nt   = (gid >> 9) & 1;
        int ks   = (gid >> 10) & 3;
        int tap  = gid >> 12;            // 0..8
        int oc = nt*32 + (lane & 31);
        int ic = ks*16 + (lane >> 5)*8 + j;
        w2p[gid] = (_Float16)w2[oc*585 + (1 + ic)*9 + tap];
    }
    if (gid < 576) {
        int oc = gid & 63, combo = gid >> 6;       // 0..8
        int rcase = combo / 3, ccase = combo % 3;
        float s = 0.0f;
        for (int kh = 0; kh < 3; kh++) {
            if ((rcase == 1 && kh == 0) || (rcase == 2 && kh == 2)) continue;
            for (int kw = 0; kw < 3; kw++) {
                if ((ccase == 1 && kw == 0) || (ccase == 2 && kw == 2)) continue;
                s += w2[oc*585 + kh*3 + kw];
            }
        }
        tsum[gid] = s;
    }
    // w1t[c][o]  (c<8, o<64)
    if (gid < 512) wpk[gid] = w1[(gid & 63)*9 + 1 + (gid >> 6)];
    // w10[o]
    if (gid < 64)  wpk[512 + gid] = w1[gid*9];
    // w3t[c][o]  (c<64, o<8)
    if (gid < 512) wpk[576 + gid] = w3[(gid & 7)*65 + 1 + (gid >> 3)];
    // w30[o]
    if (gid < 8)   wpk[1088 + gid] = w3[gid*65];
}

// ---------------- the whole ODE solve: one co-resident kernel ----------------
__global__ void __launch_bounds__(256, 2)
k_ode(const float* __restrict__ b1, const float* __restrict__ b2,
      const float* __restrict__ b3, const _Float16* __restrict__ w2p,
      const float* __restrict__ tsumg, const float* __restrict__ wpk,
      const float* __restrict__ wl, const float* __restrict__ bl,
      float* __restrict__ ybuf, float* __restrict__ y5buf,
      float* __restrict__ kb, float* __restrict__ part,
      int* __restrict__ flags, float* __restrict__ out)
{
    __shared__ __align__(16) unsigned char s_pool[55488];
    __shared__ float s_tsum[576];
    __shared__ float s_b2v[64];
    __shared__ float s_red[256];

    const int tid = threadIdx.x;
    const int nblk = gridDim.x;
    const int lane = tid & 63;
    const int m32 = lane & 31, q2 = lane >> 5;
    const int rp = tid >> 7;          // row-pair of the 4-row tile
    const int np = (tid >> 6) & 1;    // oc-half

    if (tid < 64) s_b2v[tid] = b2[tid];
    for (int i = tid; i < 576; i += 256) s_tsum[i] = tsumg[i];
    __syncthreads();

    float t = 0.0f, dt = 0.1f;
    float* ya = ybuf; float* yb = y5buf;
    float* ka = kb;  float* kg = kb + 6*(size_t)NS;

    auto wait_all = [&](int target) {
        for (;;) {
            bool ok = (__hip_atomic_load(&flags[tid], __ATOMIC_RELAXED,
                           __HIP_MEMORY_SCOPE_SYSTEM) >= target)
                   && (__hip_atomic_load(&flags[tid + 256], __ATOMIC_RELAXED,
                           __HIP_MEMORY_SCOPE_SYSTEM) >= target);
            if (__syncthreads_and((int)ok)) break;
            __builtin_amdgcn_s_sleep(2);
        }
    };

    auto eval = [&](const float* src, int nc, const float* cf, float ctv,
                    float* kout, int mode, int gev, float* partp) {
        float dtc = fminf(dt, 1.0f - t);
        float ts  = t + ctv*dtc;

        for (int tile = blockIdx.x; tile < 512; tile += nblk) {
            int b = tile >> 3, rg = tile & 7;

            // 1) zero halo columns (cols 0 & 33, 6 rows, 128 B each)
            if (tid < 96) {
                int px_id = tid >> 3, u = tid & 7;
                int row = px_id >> 1, colh = (px_id & 1) ? 33 : 0;
                *(uint4*)(s_pool + (size_t)(row*34 + colh)*272 + u*16) =
                    make_uint4(0u,0u,0u,0u);
            }

            // 2) conv1 (z-combine + 1x1 9->64 + relu) -> fp16 into LDS, 6 rows
            // wave-row map {2,3 | 1,4 | 0,5}: interior wave races ahead,
            // own-boundary wave loads immediately, halo wave spins (both flags
            // polled in parallel, per-lane).
            if (tid < 192) {
                int w = tid >> 5;
                int lr = (0x504132 >> (4*w)) & 7;
                int col = tid & 31;
                int r = rg*4 - 1 + lr;
                bool sysrow = (lr < 2) | (lr > 3);
                int pxi = lr*34 + col + 1;
                uint4* d = (uint4*)(s_pool + (size_t)pxi*272);
                if (gev > 1 && w >= 4) {
                    const int* fp = (lr == 0) ? &flags[tile-1] : &flags[tile+1];
                    bool need = (lr == 0) ? (rg > 0) : (rg < 7);
                    while (need && __hip_atomic_load(fp, __ATOMIC_RELAXED,
                                                     __HIP_MEMORY_SCOPE_SYSTEM) < gev-1)
                        __builtin_amdgcn_s_sleep(1);
                }
                if ((unsigned)r < 32u) {
                    int px = (r << 5) + col;
                    size_t pb8 = ((size_t)(b << 10) + px) << 3;
                    // batched loads: issue everything, wait once at first use
                    float kv[5][8], sv[8];
                    if (sysrow) {
                        #pragma unroll
                        for (int j = 0; j < 5; j++) if (j < nc) {
                            const float* kp = (j == 0 ? ka : kb + (size_t)j*NS) + pb8;
                            #pragma unroll
                            for (int h = 0; h < 4; h++) {
                                float2 t2 = ld_sysf2(kp + 2*h);
                                kv[j][2*h] = t2.x; kv[j][2*h+1] = t2.y;
                            }
                        }
                        #pragma unroll
                        for (int h = 0; h < 4; h++) {
                            float2 t2 = ld_sysf2(src + pb8 + 2*h);
                            sv[2*h] = t2.x; sv[2*h+1] = t2.y;
                        }
                    } else {
                        #pragma unroll
                        for (int j = 0; j < 5; j++) if (j < nc) {
                            const float* kp = (j == 0 ? ka : kb + (size_t)j*NS) + pb8;
                            float4 a4 = *(const float4*)kp;
                            float4 b4 = *(const float4*)(kp + 4);
                            kv[j][0]=a4.x; kv[j][1]=a4.y; kv[j][2]=a4.z; kv[j][3]=a4.w;
                            kv[j][4]=b4.x; kv[j][5]=b4.y; kv[j][6]=b4.z; kv[j][7]=b4.w;
                        }
                        float4 a4 = *(const float4*)(src + pb8);
                        float4 b4 = *(const float4*)(src + pb8 + 4);
                        sv[0]=a4.x; sv[1]=a4.y; sv[2]=a4.z; sv[3]=a4.w;
                        sv[4]=b4.x; sv[5]=b4.y; sv[6]=b4.z; sv[7]=b4.w;
                    }
                    float s[8] = {0,0,0,0,0,0,0,0};
                    #pragma unroll
                    for (int j = 0; j < 5; j++) if (j < nc) {
                        float a = cf[j];
                        #pragma unroll
                        for (int c = 0; c < 8; c++) s[c] = fmaf(a, kv[j][c], s[c]);
                    }
                    float zz[8];
                    #pragma unroll
                    for (int c = 0; c < 8; c++) zz[c] = sv[c] + dtc*s[c];

                    // weights via uniform global reads (scalar-cache path)
                    const float* w10 = wpk + 512;
                    float acc[64];
                    #pragma unroll
                    for (int o = 0; o < 64; o += 4) {
                        float4 wv = *(const float4*)(w10 + o);
                        float4 bv = *(const float4*)(b1 + o);
                        acc[o+0] = fmaf(ts, wv.x, bv.x);
                        acc[o+1] = fmaf(ts, wv.y, bv.y);
                        acc[o+2] = fmaf(ts, wv.z, bv.z);
                        acc[o+3] = fmaf(ts, wv.w, bv.w);
                    }
                    #pragma unroll
                    for (int c = 0; c < 8; c++) {
                        float zc = zz[c];
                        const float4* w4 = reinterpret_cast<const float4*>(wpk + c*64);
                        #pragma unroll
                        for (int qq = 0; qq < 16; qq++) {
                            float4 wq = w4[qq];
                            acc[4*qq+0] = fmaf(wq.x, zc, acc[4*qq+0]);
                            acc[4*qq+1] = fmaf(wq.y, zc, acc[4*qq+1]);
                            acc[4*qq+2] = fmaf(wq.z, zc, acc[4*qq+2]);
                            acc[4*qq+3] = fmaf(wq.w, zc, acc[4*qq+3]);
                        }
                    }
                    unsigned hbuf[32];
                    #pragma unroll
                    for (int i = 0; i < 32; i++) {
                        union { _Float16 h[2]; unsigned u; } p;
                        p.h[0] = (_Float16)fmaxf(acc[2*i],   0.0f);
                        p.h[1] = (_Float16)fmaxf(acc[2*i+1], 0.0f);
                        hbuf[i] = p.u;
                    }
                    const uint4* hv = (const uint4*)hbuf;
                    #pragma unroll
                    for (int i = 0; i < 8; i++) d[i] = hv[i];
                } else {
                    uint4 z4 = make_uint4(0u,0u,0u,0u);
                    #pragma unroll
                    for (int i = 0; i < 8; i++) d[i] = z4;
                }
            }
            __syncthreads();

            // 3) conv2: 3x3 65->64 single-pass fp16 via 32x32x16 MFMA
            f32x16 acc2[2];   // [ri]
            acc2[0] = (f32x16)(0.0f);
            acc2[1] = (f32x16)(0.0f);

            for (int cc = 0; cc < 2; cc++) {
                #pragma unroll 1
                for (int kh = 0; kh < 3; kh++) {
                    #pragma unroll
                    for (int kw = 0; kw < 3; kw++) {
                        int tap = kh*3 + kw;
                        #pragma unroll
                        for (int s = 0; s < 2; s++) {
                            int ks = cc*2 + s;
                            hfrag8 bh = *(const hfrag8*)
                                (w2p + (size_t)((tap*4 + ks)*2 + np)*512 + lane*8);
                            int aoff = ks*32 + q2*16;
                            #pragma unroll
                            for (int ri = 0; ri < 2; ri++) {
                                int lr = rp*2 + ri + kh;
                                hfrag8 ah = *(const hfrag8*)(s_pool
                                    + (size_t)(lr*34 + m32 + kw)*272 + aoff);
                                acc2[ri] = __builtin_amdgcn_mfma_f32_32x32x16_f16(
                                    ah, bh, acc2[ri], 0, 0, 0);
                            }
                        }
                    }
                }
            }
            __syncthreads();   // before h2 overlay on pool

            // 4) epilogue: t-channel + bias + relu -> LDS h2, oc-major stride 129
            {
                float* s_h2 = (float*)s_pool;
                int oc = np*32 + m32;
                float tb = s_b2v[oc];
                #pragma unroll
                for (int ri = 0; ri < 2; ri++) {
                    int lrow = rp*2 + ri;
                    int r_out = rg*4 + lrow;
                    int rcase = (r_out == 0) ? 1 : ((r_out == 31) ? 2 : 0);
                    #pragma unroll
                    for (int reg = 0; reg < 16; reg++) {
                        int cpos = (reg & 3) + 8*(reg >> 2) + 4*q2;
                        int ccase = (cpos == 0) ? 1 : ((cpos == 31) ? 2 : 0);
                        float tsv = s_tsum[(rcase*3 + ccase)*64 + oc];
                        s_h2[oc*129 + lrow*32 + cpos] =
                            fmaxf(acc2[ri][reg] + ts*tsv + tb, 0.0f);
                    }
                }
            }
            __syncthreads();

            // 5) conv3 (1x1 65->8) + mode epilogues (scope per row class)
            if (tid < 128) {
                const float* s_h2 = (const float*)s_pool;
                const float* w3t = wpk + 576;
                const float* w30 = wpk + 1088;
                float a3[8];
                #pragma unroll
                for (int o = 0; o < 8; o++) a3[o] = fmaf(ts, w30[o], b3[o]);
                #pragma unroll 8
                for (int c = 0; c < 64; c++) {
                    float xv = s_h2[c*129 + tid];
                    float4 wA = *(const float4*)(w3t + c*8);
                    float4 wB = *(const float4*)(w3t + c*8 + 4);
                    a3[0] = fmaf(wA.x, xv, a3[0]);
                    a3[1] = fmaf(wA.y, xv, a3[1]);
                    a3[2] = fmaf(wA.z, xv, a3[2]);
                    a3[3] = fmaf(wA.w, xv, a3[3]);
                    a3[4] = fmaf(wB.x, xv, a3[4]);
                    a3[5] = fmaf(wB.y, xv, a3[5]);
                    a3[6] = fmaf(wB.z, xv, a3[6]);
                    a3[7] = fmaf(wB.w, xv, a3[7]);
                }
                int lrow = tid >> 5;
                bool sysrow = (lrow == 0) | (lrow == 3);
                int px = rg*128 + tid;
                size_t pb8 = ((size_t)(b << 10) + px) << 3;
                st8(kout + pb8, a3, sysrow);
                if (mode == 1) {
                    float kv1[8], kv3[8], kv4[8], kv5[8], yv[8], r8[8];
                    ld8(ka + pb8, kv1, sysrow);
                    ld8(kb + 2*(size_t)NS + pb8, kv3, sysrow);
                    ld8(kb + 3*(size_t)NS + pb8, kv4, sysrow);
                    ld8(kb + 4*(size_t)NS + pb8, kv5, sysrow);
                    ld8(ya + pb8, yv, sysrow);
                    #pragma unroll
                    for (int c = 0; c < 8; c++)
                        r8[c] = yv[c] + dtc*(B1c*kv1[c] + B3c*kv3[c] + B4c*kv4[c]
                                             + B5c*kv5[c] + B6c*a3[c]);
                    st8(yb + pb8, r8, sysrow);
                } else if (mode == 2) {
                    float kv1[8], kv3[8], kv4[8], kv5[8], kv6[8], yv[8], y5v[8];
                    ld8(ka + pb8, kv1, sysrow);
                    ld8(kb + 2*(size_t)NS + pb8, kv3, sysrow);
                    ld8(kb + 3*(size_t)NS + pb8, kv4, sysrow);
                    ld8(kb + 4*(size_t)NS + pb8, kv5, sysrow);
                    ld8(kb + 5*(size_t)NS + pb8, kv6, sysrow);
                    ld8(ya + pb8, yv, sysrow);
                    ld8(yb + pb8, y5v, sysrow);
                    float ls = 0.0f;
                    #pragma unroll
                    for (int c = 0; c < 8; c++) {
                        float e = dtc*(E1c*kv1[c] + E3c*kv3[c] + E4c*kv4[c]
                                       + E5c*kv5[c] + E6c*kv6[c] + E7c*a3[c]);
                        float tol = ATOL + RTOL*fmaxf(fabsf(yv[c]), fabsf(y5v[c]));
                        float rr = e / tol;
                        ls += rr*rr;
                    }
                    s_red[tid] = ls;
                }
            }
            if (mode == 2) {
                if (tid >= 128) s_red[tid] = 0.0f;
                __syncthreads();
                for (int sft = 128; sft > 0; sft >>= 1) {
                    if (tid < sft) s_red[tid] += s_red[tid + sft];
                    __syncthreads();
                }
                if (tid == 0) st_sysf(&partp[tile], s_red[0]);
            }
            // release: syncthreads drains vmcnt (sys stores at L3), then flag
            __syncthreads();
            if (tid == 0)
                __hip_atomic_store(&flags[tile], gev, __ATOMIC_RELAXED,
                                   __HIP_MEMORY_SCOPE_SYSTEM);
        }
    };

    int gev = 1;
    eval(ya, 0, g_cf[5], 0.0f, ka, 0, gev, part);   // k1 = f(t0, y0)
    gev++;

    for (int st = 0; st < 24; st++) {
        if (t >= 1.0f - 1e-7f) break;
        float* partp = part + (size_t)(st & 1)*512;
        for (int e = 0; e < 6; e++) {
            int nc = (e < 5) ? e + 1 : 0;
            const float* src = (e == 5) ? yb : ya;
            float* kout = (e < 5) ? kb + (size_t)(e + 1)*NS : kg;
            int mode = (e == 4) ? 1 : ((e == 5) ? 2 : 0);
            eval(src, nc, g_cf[e], g_ct[e], kout, mode, gev, partp);
            gev++;
        }
        wait_all(gev - 1);   // all tiles finished the err eval (partials at L3)
        float v = ld_sysf(&partp[tid]) + ld_sysf(&partp[tid + 256]);
        s_red[tid] = v;
        __syncthreads();
        for (int sft = 128; sft > 0; sft >>= 1) {
            if (tid < sft) s_red[tid] += s_red[tid + sft];
            __syncthreads();
        }
        float red0 = s_red[0];
        __syncthreads();
        float err_norm = sqrtf(red0 / (float)NS);
        float dtc = fminf(dt, 1.0f - t);
        bool adv = (err_norm <= 1.0f);
        if (adv) {
            t = t + dtc;
            float* tmp = ya; ya = yb; yb = tmp;   // y <- y5
            tmp = ka; ka = kg; kg = tmp;          // k1 <- k7 (FSAL)
        }
        float safe = fmaxf(err_norm, 1e-10f);
        float factor = fminf(fmaxf(0.9f*powf(safe, -0.2f), 0.2f), 10.0f);
        dt = dtc*factor;
    }

    // flush private interior rows of final y to L3, then publish + wait
    for (int tile = blockIdx.x; tile < 512; tile += nblk) {
        int b = tile >> 3, rg = tile & 7;
        if (tid < 128) {
            int lrow = tid >> 5;
            if (lrow == 1 || lrow == 2) {
                int px = rg*128 + tid;
                float* yp = ya + (((size_t)(b << 10) + px) << 3);
                float4 v0 = *(const float4*)yp;
                float4 v1 = *(const float4*)(yp + 4);
                st_sysf2(yp,     v0.x, v0.y);
                st_sysf2(yp + 2, v0.z, v0.w);
                st_sysf2(yp + 4, v1.x, v1.y);
                st_sysf2(yp + 6, v1.z, v1.w);
            }
        }
    }
    __syncthreads();   // drains the sys stores of every wave
    for (int tile = blockIdx.x; tile < 512; tile += nblk)
        if (tid == 0)
            __hip_atomic_store(&flags[tile], gev, __ATOMIC_RELAXED,
                               __HIP_MEMORY_SCOPE_SYSTEM);
    wait_all(gev);

    // final linear head: y is px-major [b][px][8]; wl flat index = c*1024+px
    for (int bh = blockIdx.x; bh < 64; bh += nblk) {
        float* s_hred = (float*)s_pool;   // 10*256 floats overlay
        float acc[10];
        #pragma unroll
        for (int m = 0; m < 10; m++) acc[m] = 0.0f;
        for (int px = tid; px < 1024; px += 256) {
            const float* yp = ya + (((size_t)(bh << 10) + px) << 3);
            float yv[8];
            #pragma unroll
            for (int h = 0; h < 4; h++) {
                float2 v = ld_sysf2(yp + 2*h);
                yv[2*h] = v.x; yv[2*h+1] = v.y;
            }
            #pragma unroll
            for (int c = 0; c < 8; c++) {
                float v = yv[c];
                #pragma unroll
                for (int m = 0; m < 10; m++)
                    acc[m] = fmaf(v, wl[(size_t)m*8192 + (c << 10) + px], acc[m]);
            }
        }
        #pragma unroll
        for (int m = 0; m < 10; m++) s_hred[m*256 + tid] = acc[m];
        __syncthreads();
        for (int sft = 128; sft > 0; sft >>= 1) {
            if (tid < sft) {
                #pragma unroll
                for (int m = 0; m < 10; m++)
                    s_hred[m*256 + tid] += s_hred[m*256 + tid + sft];
            }
            __syncthreads();
        }
        if (tid < 10) out[bh*10 + tid] = s_hred[tid*256] + bl[tid];
        __syncthreads();
    }
}

// ---------------- host ----------------
extern "C" void kernel_launch(void* const* d_in, const int* in_sizes, int n_in,
                              void* d_out, int out_size, void* d_ws, size_t ws_size,
                              hipStream_t stream)
{
    const float* x  = (const float*)d_in[0];
    const float* w1 = (const float*)d_in[1];
    const float* b1 = (const float*)d_in[2];
    const float* w2 = (const float*)d_in[3];
    const float* b2 = (const float*)d_in[4];
    const float* w3 = (const float*)d_in[5];
    const float* b3 = (const float*)d_in[6];
    const float* wl = (const float*)d_in[7];
    const float* bl = (const float*)d_in[8];
    float* out = (float*)d_out;

    float* F = (float*)d_ws;
    float* part = F + OFF_PART;
    int*   flags = (int*)(F + OFF_FLAG);
    unsigned* cnt = (unsigned*)(F + OFF_CNT);
    float* tsum = F + OFF_TSUM;
    _Float16* w2p = (_Float16*)(F + OFF_W2P);
    float* y    = F + OFF_Y;
    float* y5   = F + OFF_Y5;
    float* kbp  = F + OFF_K;
    float* wpk  = F + OFF_WPK;

    k_init<<<NS/256, 256, 0, stream>>>(x, y, flags, cnt);
    k_prepack<<<144, 256, 0, stream>>>(w1, w2, w3, w2p, tsum, wpk);

    // plain launch; grid capped at guaranteed co-resident capacity
    int maxb = 0;
    if (hipOccupancyMaxActiveBlocksPerMultiprocessor(&maxb,
            reinterpret_cast<const void*>(k_ode), 256, 0) != hipSuccess || maxb < 1)
        maxb = 1;
    int cus = 256;
    {
        int dev = 0;
        hipGetDevice(&dev);
        hipDeviceProp_t prop;
        if (hipGetDeviceProperties(&prop, dev) == hipSuccess && prop.multiProcessorCount > 0)
            cus = prop.multiProcessorCount;
    }
    long cap = (long)maxb * (long)cus;
    int gridn = (int)((cap < 512) ? cap : 512);
    if (gridn < 16) gridn = 16;

    k_ode<<<gridn, 256, 0, stream>>>(b1, b2, b3, w2p, tsum, wpk, wl, bl,
                                     y, y5, kbp, part, flags, out);
}

// Round 2
// 474.093 us; speedup vs baseline: 1.3203x; 1.1347x over previous
//
#include <hip/hip_runtime.h>
#include <math.h>

namespace {
constexpr int BN = 64;
constexpr int HW = 1024;
constexpr int NS = BN*8*HW;      // 524288

constexpr float C2f = 0.2f, C3f = 0.3f, C4f = 0.8f, C5f = (float)(8.0/9.0);
constexpr float A21 = 0.2f;
constexpr float A31 = (float)(3.0/40.0),  A32 = (float)(9.0/40.0);
constexpr float A41 = (float)(44.0/45.0), A42 = (float)(-56.0/15.0), A43 = (float)(32.0/9.0);
constexpr float A51 = (float)(19372.0/6561.0), A52 = (float)(-25360.0/2187.0),
                A53 = (float)(64448.0/6561.0), A54 = (float)(-212.0/729.0);
constexpr float A61 = (float)(9017.0/3168.0), A62 = (float)(-355.0/33.0),
                A63 = (float)(46732.0/5247.0), A64 = (float)(49.0/176.0),
                A65 = (float)(-5103.0/18656.0);
constexpr float B1c = (float)(35.0/384.0), B3c = (float)(500.0/1113.0),
                B4c = (float)(125.0/192.0), B5c = (float)(-2187.0/6784.0),
                B6c = (float)(11.0/84.0);
constexpr float E1c = (float)(71.0/57600.0), E3c = (float)(-71.0/16695.0),
                E4c = (float)(71.0/1920.0), E5c = (float)(-17253.0/339200.0),
                E6c = (float)(22.0/525.0),  E7c = (float)(-1.0/40.0);
constexpr float RTOL = 1e-3f, ATOL = 1e-3f;

// ws layout (floats / ints)
constexpr size_t OFF_PART = 0;        // 1024 floats (double-buffered by step parity)
constexpr size_t OFF_FLAG = 1024;     // 512 ints
constexpr size_t OFF_CNT  = 1536;     // 1 int (+pad) [unused, kept]
constexpr size_t OFF_TSUM = 1600;     // 576
constexpr size_t OFF_W2P  = 2176;     // 36864 halfs = 18432 floats
constexpr size_t OFF_Y    = 20608;    // y buffers px-major: [b][px][8]
constexpr size_t OFF_Y5   = OFF_Y  + (size_t)NS;
constexpr size_t OFF_K    = OFF_Y5 + (size_t)NS;   // 7*NS (k1..k7, px-major)
constexpr size_t OFF_WPK  = OFF_K + (size_t)7*NS;  // w1t(512) w10(64) w3t(512) w30(8)
}

__constant__ float g_cf[6][5] = {
    {A21, 0, 0, 0, 0},
    {A31, A32, 0, 0, 0},
    {A41, A42, A43, 0, 0},
    {A51, A52, A53, A54, 0},
    {A61, A62, A63, A64, A65},
    {0, 0, 0, 0, 0}};
__constant__ float g_ct[6] = {C2f, C3f, C4f, C5f, 1.0f, 1.0f};

typedef _Float16 hfrag8 __attribute__((ext_vector_type(8)));
typedef float f32x16 __attribute__((ext_vector_type(16)));

// ---- system-scope (L3-coherent) accessors ----
__device__ __forceinline__ float ld_sysf(const float* p) {
    return __hip_atomic_load(p, __ATOMIC_RELAXED, __HIP_MEMORY_SCOPE_SYSTEM);
}
__device__ __forceinline__ float2 ld_sysf2(const float* p) {
    union { unsigned long long u; float2 f; } c;
    c.u = __hip_atomic_load((const unsigned long long*)p, __ATOMIC_RELAXED,
                            __HIP_MEMORY_SCOPE_SYSTEM);
    return c.f;
}
__device__ __forceinline__ void st_sysf(float* p, float v) {
    __hip_atomic_store(p, v, __ATOMIC_RELAXED, __HIP_MEMORY_SCOPE_SYSTEM);
}
__device__ __forceinline__ void st_sysf2(float* p, float a, float b) {
    union { unsigned long long u; float2 f; } c;
    c.f = make_float2(a, b);
    __hip_atomic_store((unsigned long long*)p, c.u, __ATOMIC_RELAXED,
                       __HIP_MEMORY_SCOPE_SYSTEM);
}

// 8-float load/store with scope selected by row class (sys = boundary row)
__device__ __forceinline__ void ld8(const float* p, float* v, bool sys) {
    if (sys) {
        #pragma unroll
        for (int h = 0; h < 4; h++) {
            float2 t = ld_sysf2(p + 2*h);
            v[2*h] = t.x; v[2*h+1] = t.y;
        }
    } else {
        float4 a = *(const float4*)p;
        float4 b = *(const float4*)(p + 4);
        v[0]=a.x; v[1]=a.y; v[2]=a.z; v[3]=a.w;
        v[4]=b.x; v[5]=b.y; v[6]=b.z; v[7]=b.w;
    }
}
__device__ __forceinline__ void st8(float* p, const float* v, bool sys) {
    if (sys) {
        st_sysf2(p,     v[0], v[1]);
        st_sysf2(p + 2, v[2], v[3]);
        st_sysf2(p + 4, v[4], v[5]);
        st_sysf2(p + 6, v[6], v[7]);
    } else {
        *(float4*)p       = make_float4(v[0], v[1], v[2], v[3]);
        *(float4*)(p + 4) = make_float4(v[4], v[5], v[6], v[7]);
    }
}

// ---------------- init ----------------
__global__ __launch_bounds__(256)
void k_init(const float* __restrict__ x, float* __restrict__ y,
            int* __restrict__ flags, unsigned* __restrict__ cnt)
{
    int idx = blockIdx.x*256 + threadIdx.x;           // < NS
    int b = idx >> 13, px = (idx >> 3) & 1023, c = idx & 7;
    y[idx] = (c < 3) ? x[(size_t)(b*3 + c)*1024 + px] : 0.0f;
    if (idx < 512) flags[idx] = 0;
    if (idx == 600) *cnt = 0u;
}

// ---------------- prepack: w2 fp16 frag order + t-channel table + w1/w3 transposes ----------------
__global__ __launch_bounds__(256)
void k_prepack(const float* __restrict__ w1, const float* __restrict__ w2,
               const float* __restrict__ w3, _Float16* __restrict__ w2p,
               float* __restrict__ tsum, float* __restrict__ wpk)
{
    int gid = blockIdx.x*256 + threadIdx.x;
    if (gid < 36864) {
        int j    = gid & 7;
        int lane = (gid >> 3) & 63;
        int nt   = (gid >> 9) & 1;
        int ks   = (gid >> 10) & 3;
        int tap  = gid >> 12;            // 0..8
        int oc = nt*32 + (lane & 31);
        int ic = ks*16 + (lane >> 5)*8 + j;
        w2p[gid] = (_Float16)w2[oc*585 + (1 + ic)*9 + tap];
    }
    if (gid < 576) {
        int oc = gid & 63, combo = gid >> 6;       // 0..8
        int rcase = combo / 3, ccase = combo % 3;
        float s = 0.0f;
        for (int kh = 0; kh < 3; kh++) {
            if ((rcase == 1 && kh == 0) || (rcase == 2 && kh == 2)) continue;
            for (int kw = 0; kw < 3; kw++) {
                if ((ccase == 1 && kw == 0) || (ccase == 2 && kw == 2)) continue;
                s += w2[oc*585 + kh*3 + kw];
            }
        }
        tsum[gid] = s;
    }
    // w1t: wpk[c*64 + o] = w1[o*9 + 1 + c]
    if (gid < 512) wpk[gid] = w1[(gid & 63)*9 + 1 + (gid >> 6)];
    // w10[o]
    if (gid < 64)  wpk[512 + gid] = w1[gid*9];
    // w3t: wpk[576 + c*8 + o] = w3[o*65 + 1 + c]
    if (gid < 512) wpk[576 + gid] = w3[(gid & 7)*65 + 1 + (gid >> 3)];
    // w30[o]
    if (gid < 8)   wpk[1088 + gid] = w3[gid*65];
}

// ---------------- the whole ODE solve: one co-resident kernel ----------------
// R2: conv1 and conv3 moved to MFMA. conv2 operands transposed
// (mfma(w2,act)) so its C is px-per-lane -> h2 written px-major fp16
// (stride 144B) = conv3's B-fragment layout directly.
__global__ void __launch_bounds__(256, 2)
k_ode(const float* __restrict__ b1, const float* __restrict__ b2,
      const float* __restrict__ b3, const _Float16* __restrict__ w2p,
      const float* __restrict__ tsumg, const float* __restrict__ wpk,
      const float* __restrict__ wl, const float* __restrict__ bl,
      float* __restrict__ ybuf, float* __restrict__ y5buf,
      float* __restrict__ kb, float* __restrict__ part,
      int* __restrict__ flags, float* __restrict__ out)
{
    __shared__ __align__(16) unsigned char s_pool[55488];
    __shared__ __align__(16) _Float16 s_z[1552];   // 192 frags + zero slot @192
    __shared__ float s_tsum[576];
    __shared__ float s_b2v[64], s_b1v[64], s_w10v[64];
    __shared__ float s_w30v[8], s_b3v[8];
    __shared__ float s_red[256];

    const int tid = threadIdx.x;
    const int nblk = gridDim.x;
    const int lane = tid & 63;
    const int m32 = lane & 31, q2 = lane >> 5;
    const int rp = tid >> 7;          // row-pair for conv2
    const int np = (tid >> 6) & 1;    // oc-half for conv2
    const int wid = tid >> 6;         // wave id

    if (tid < 64) {
        s_b2v[tid] = b2[tid];
        s_b1v[tid] = b1[tid];
        s_w10v[tid] = wpk[512 + tid];
    }
    if (tid < 8) { s_w30v[tid] = wpk[1088 + tid]; s_b3v[tid] = b3[tid]; }
    for (int i = tid; i < 576; i += 256) s_tsum[i] = tsumg[i];
    if (tid < 8) s_z[192*8 + tid] = (_Float16)0.0f;   // zero frag slot
    __syncthreads();

    // resident weight fragments (built once; A-operand layout: row=lane&31, k=q2*8+j)
    const int oct1 = wid >> 1;        // conv1 oc-tile for this wave
    hfrag8 w1f;
    #pragma unroll
    for (int j = 0; j < 8; j++)
        w1f[j] = q2 ? (_Float16)0.0f : (_Float16)wpk[j*64 + oct1*32 + m32];
    hfrag8 w3f[4];
    #pragma unroll
    for (int kst = 0; kst < 4; kst++)
        #pragma unroll
        for (int j = 0; j < 8; j++) {
            int ch = kst*16 + q2*8 + j;
            w3f[kst][j] = (m32 < 8) ? (_Float16)wpk[576 + ch*8 + m32]
                                    : (_Float16)0.0f;
        }

    float t = 0.0f, dt = 0.1f;
    float* ya = ybuf; float* yb = y5buf;
    float* ka = kb;  float* kg = kb + 6*(size_t)NS;

    auto wait_all = [&](int target) {
        for (;;) {
            bool ok = (__hip_atomic_load(&flags[tid], __ATOMIC_RELAXED,
                           __HIP_MEMORY_SCOPE_SYSTEM) >= target)
                   && (__hip_atomic_load(&flags[tid + 256], __ATOMIC_RELAXED,
                           __HIP_MEMORY_SCOPE_SYSTEM) >= target);
            if (__syncthreads_and((int)ok)) break;
            __builtin_amdgcn_s_sleep(2);
        }
    };

    auto eval = [&](const float* src, int nc, const float* cf, float ctv,
                    float* kout, int mode, int gev, float* partp) {
        float dtc = fminf(dt, 1.0f - t);
        float ts  = t + ctv*dtc;

        for (int tile = blockIdx.x; tile < 512; tile += nblk) {
            int b = tile >> 3, rg = tile & 7;

            // P1) zero halo columns (cols 0 & 33, 6 rows, 128 B each)
            if (tid < 96) {
                int px_id = tid >> 3, u = tid & 7;
                int row = px_id >> 1, colh = (px_id & 1) ? 33 : 0;
                *(uint4*)(s_pool + (size_t)(row*34 + colh)*272 + u*16) =
                    make_uint4(0u,0u,0u,0u);
            }

            // P2a) z-combine -> fp16 frags in s_z (wave-row map {2,3|1,4|0,5})
            if (tid < 192) {
                int w = tid >> 5;
                int lr = (0x504132 >> (4*w)) & 7;
                int col = tid & 31;
                int r = rg*4 - 1 + lr;
                bool sysrow = (lr < 2) | (lr > 3);
                if (gev > 1 && w >= 4) {
                    const int* fp = (lr == 0) ? &flags[tile-1] : &flags[tile+1];
                    bool need = (lr == 0) ? (rg > 0) : (rg < 7);
                    while (need && __hip_atomic_load(fp, __ATOMIC_RELAXED,
                                                     __HIP_MEMORY_SCOPE_SYSTEM) < gev-1)
                        __builtin_amdgcn_s_sleep(1);
                }
                union { _Float16 h[8]; uint4 u; } pz;
                if ((unsigned)r < 32u) {
                    int px = (r << 5) + col;
                    size_t pb8 = ((size_t)(b << 10) + px) << 3;
                    float kv[5][8], sv[8];
                    if (sysrow) {
                        #pragma unroll
                        for (int j = 0; j < 5; j++) if (j < nc) {
                            const float* kp = (j == 0 ? ka : kb + (size_t)j*NS) + pb8;
                            #pragma unroll
                            for (int h = 0; h < 4; h++) {
                                float2 t2 = ld_sysf2(kp + 2*h);
                                kv[j][2*h] = t2.x; kv[j][2*h+1] = t2.y;
                            }
                        }
                        #pragma unroll
                        for (int h = 0; h < 4; h++) {
                            float2 t2 = ld_sysf2(src + pb8 + 2*h);
                            sv[2*h] = t2.x; sv[2*h+1] = t2.y;
                        }
                    } else {
                        #pragma unroll
                        for (int j = 0; j < 5; j++) if (j < nc) {
                            const float* kp = (j == 0 ? ka : kb + (size_t)j*NS) + pb8;
                            float4 a4 = *(const float4*)kp;
                            float4 b4 = *(const float4*)(kp + 4);
                            kv[j][0]=a4.x; kv[j][1]=a4.y; kv[j][2]=a4.z; kv[j][3]=a4.w;
                            kv[j][4]=b4.x; kv[j][5]=b4.y; kv[j][6]=b4.z; kv[j][7]=b4.w;
                        }
                        float4 a4 = *(const float4*)(src + pb8);
                        float4 b4 = *(const float4*)(src + pb8 + 4);
                        sv[0]=a4.x; sv[1]=a4.y; sv[2]=a4.z; sv[3]=a4.w;
                        sv[4]=b4.x; sv[5]=b4.y; sv[6]=b4.z; sv[7]=b4.w;
                    }
                    float s[8] = {0,0,0,0,0,0,0,0};
                    #pragma unroll
                    for (int j = 0; j < 5; j++) if (j < nc) {
                        float a = cf[j];
                        #pragma unroll
                        for (int c = 0; c < 8; c++) s[c] = fmaf(a, kv[j][c], s[c]);
                    }
                    #pragma unroll
                    for (int c = 0; c < 8; c++)
                        pz.h[c] = (_Float16)(sv[c] + dtc*s[c]);
                } else {
                    pz.u = make_uint4(0u,0u,0u,0u);
                }
                *(uint4*)(s_z + (size_t)(lr*32 + col)*8) = pz.u;
            }
            __syncthreads();

            // P2b) conv1 via MFMA: 6 rows x 2 oc-tiles = 12 MFMAs over 4 waves
            {
                int pgbase = (wid & 1)*3;
                #pragma unroll
                for (int i = 0; i < 3; i++) {
                    int pxg = pgbase + i;
                    int r = rg*4 - 1 + pxg;
                    bool valid = ((unsigned)r < 32u);
                    const _Float16* zp = s_z + (q2 ? (size_t)192*8
                                                   : (size_t)(pxg*32 + m32)*8);
                    hfrag8 bz = *(const hfrag8*)zp;
                    f32x16 a1 = (f32x16)(0.0f);
                    a1 = __builtin_amdgcn_mfma_f32_32x32x16_f16(w1f, bz, a1, 0,0,0);
                    unsigned words[8];
                    #pragma unroll
                    for (int pr = 0; pr < 8; pr++) {
                        int r0 = 2*pr;
                        int oc0 = oct1*32 + (r0&3) + 8*(r0>>2) + 4*q2;
                        float v0 = valid ? fmaxf(a1[r0]   + ts*s_w10v[oc0]
                                                 + s_b1v[oc0],   0.0f) : 0.0f;
                        float v1 = valid ? fmaxf(a1[r0+1] + ts*s_w10v[oc0+1]
                                                 + s_b1v[oc0+1], 0.0f) : 0.0f;
                        union { _Float16 h[2]; unsigned u; } pk;
                        pk.h[0] = (_Float16)v0; pk.h[1] = (_Float16)v1;
                        words[pr] = pk.u;
                    }
                    unsigned char* basep = s_pool
                        + (size_t)(pxg*34 + m32 + 1)*272 + oct1*64 + q2*8;
                    #pragma unroll
                    for (int wq = 0; wq < 4; wq++)
                        *(uint2*)(basep + wq*16) =
                            make_uint2(words[2*wq], words[2*wq+1]);
                }
            }
            __syncthreads();

            // P3) conv2: 3x3 65->64, transposed operands: mfma(w2, act)
            f32x16 acc2[2];
            acc2[0] = (f32x16)(0.0f);
            acc2[1] = (f32x16)(0.0f);
            for (int cc = 0; cc < 2; cc++) {
                #pragma unroll 1
                for (int kh = 0; kh < 3; kh++) {
                    #pragma unroll
                    for (int kw = 0; kw < 3; kw++) {
                        int tap = kh*3 + kw;
                        #pragma unroll
                        for (int s = 0; s < 2; s++) {
                            int ks = cc*2 + s;
                            hfrag8 aw = *(const hfrag8*)
                                (w2p + (size_t)((tap*4 + ks)*2 + np)*512 + lane*8);
                            int aoff = ks*32 + q2*16;
                            #pragma unroll
                            for (int ri = 0; ri < 2; ri++) {
                                int lr = rp*2 + ri + kh;
                                hfrag8 bact = *(const hfrag8*)(s_pool
                                    + (size_t)(lr*34 + m32 + kw)*272 + aoff);
                                acc2[ri] = __builtin_amdgcn_mfma_f32_32x32x16_f16(
                                    aw, bact, acc2[ri], 0, 0, 0);
                            }
                        }
                    }
                }
            }
            __syncthreads();   // before h2 overlay on pool

            // P4) epilogue: t-channel + bias + relu -> h2 px-major fp16, stride 144B
            {
                int ccase = (m32 == 0) ? 1 : ((m32 == 31) ? 2 : 0);
                #pragma unroll
                for (int ri = 0; ri < 2; ri++) {
                    int pg = rp*2 + ri;
                    int r_out = rg*4 + pg;
                    int rcase = (r_out == 0) ? 1 : ((r_out == 31) ? 2 : 0);
                    const float* tsb = &s_tsum[(rcase*3 + ccase)*64];
                    int px = pg*32 + m32;
                    unsigned words[8];
                    #pragma unroll
                    for (int pr = 0; pr < 8; pr++) {
                        int r0 = 2*pr;
                        int oc0 = np*32 + (r0&3) + 8*(r0>>2) + 4*q2;
                        float v0 = fmaxf(acc2[ri][r0]   + ts*tsb[oc0]
                                         + s_b2v[oc0],   0.0f);
                        float v1 = fmaxf(acc2[ri][r0+1] + ts*tsb[oc0+1]
                                         + s_b2v[oc0+1], 0.0f);
                        union { _Float16 h[2]; unsigned u; } pk;
                        pk.h[0] = (_Float16)v0; pk.h[1] = (_Float16)v1;
                        words[pr] = pk.u;
                    }
                    unsigned char* basep = s_pool + (size_t)px*144
                                           + np*64 + q2*8;
                    #pragma unroll
                    for (int wq = 0; wq < 4; wq++)
                        *(uint2*)(basep + wq*16) =
                            make_uint2(words[2*wq], words[2*wq+1]);
                }
            }
            __syncthreads();

            // P5) conv3 via MFMA (K=64 in 4 steps) + mode epilogues
            {
                f32x16 a3a = (f32x16)(0.0f);
                const unsigned char* hb = (const unsigned char*)s_pool;
                #pragma unroll
                for (int kst = 0; kst < 4; kst++) {
                    hfrag8 bh2 = *(const hfrag8*)(hb
                        + (size_t)(wid*32 + m32)*144 + kst*32 + q2*16);
                    a3a = __builtin_amdgcn_mfma_f32_32x32x16_f16(
                        w3f[kst], bh2, a3a, 0, 0, 0);
                }
                // gather the other oc-half from partner lane (lane ^ 32)
                float a3[8];
                #pragma unroll
                for (int r = 0; r < 4; r++) {
                    float own = a3a[r];
                    float oth = __shfl(own, lane ^ 32, 64);
                    a3[r]     = q2 ? oth : own;
                    a3[4 + r] = q2 ? own : oth;
                }
                float ls = 0.0f;
                if (q2 == 0) {
                    #pragma unroll
                    for (int c = 0; c < 8; c++)
                        a3[c] += fmaf(ts, s_w30v[c], s_b3v[c]);
                    bool sysrow = (wid == 0) | (wid == 3);
                    int px = rg*128 + wid*32 + m32;
                    size_t pb8 = ((size_t)(b << 10) + px) << 3;
                    st8(kout + pb8, a3, sysrow);
                    if (mode == 1) {
                        float kv1[8], kv3[8], kv4[8], kv5[8], yv[8], r8[8];
                        ld8(ka + pb8, kv1, sysrow);
                        ld8(kb + 2*(size_t)NS + pb8, kv3, sysrow);
                        ld8(kb + 3*(size_t)NS + pb8, kv4, sysrow);
                        ld8(kb + 4*(size_t)NS + pb8, kv5, sysrow);
                        ld8(ya + pb8, yv, sysrow);
                        #pragma unroll
                        for (int c = 0; c < 8; c++)
                            r8[c] = yv[c] + dtc*(B1c*kv1[c] + B3c*kv3[c]
                                    + B4c*kv4[c] + B5c*kv5[c] + B6c*a3[c]);
                        st8(yb + pb8, r8, sysrow);
                    } else if (mode == 2) {
                        float kv1[8], kv3[8], kv4[8], kv5[8], kv6[8], yv[8], y5v[8];
                        ld8(ka + pb8, kv1, sysrow);
                        ld8(kb + 2*(size_t)NS + pb8, kv3, sysrow);
                        ld8(kb + 3*(size_t)NS + pb8, kv4, sysrow);
                        ld8(kb + 4*(size_t)NS + pb8, kv5, sysrow);
                        ld8(kb + 5*(size_t)NS + pb8, kv6, sysrow);
                        ld8(ya + pb8, yv, sysrow);
                        ld8(yb + pb8, y5v, sysrow);
                        #pragma unroll
                        for (int c = 0; c < 8; c++) {
                            float e = dtc*(E1c*kv1[c] + E3c*kv3[c] + E4c*kv4[c]
                                           + E5c*kv5[c] + E6c*kv6[c] + E7c*a3[c]);
                            float tol = ATOL + RTOL*fmaxf(fabsf(yv[c]), fabsf(y5v[c]));
                            float rr = e / tol;
                            ls += rr*rr;
                        }
                    }
                }
                if (mode == 2) {
                    s_red[tid] = ls;
                    __syncthreads();
                    for (int sft = 128; sft > 0; sft >>= 1) {
                        if (tid < sft) s_red[tid] += s_red[tid + sft];
                        __syncthreads();
                    }
                    if (tid == 0) st_sysf(&partp[tile], s_red[0]);
                }
            }
            // release: syncthreads drains vmcnt (sys stores at L3), then flag
            __syncthreads();
            if (tid == 0)
                __hip_atomic_store(&flags[tile], gev, __ATOMIC_RELAXED,
                                   __HIP_MEMORY_SCOPE_SYSTEM);
        }
    };

    int gev = 1;
    eval(ya, 0, g_cf[5], 0.0f, ka, 0, gev, part);   // k1 = f(t0, y0)
    gev++;

    for (int st = 0; st < 24; st++) {
        if (t >= 1.0f - 1e-7f) break;
        float* partp = part + (size_t)(st & 1)*512;
        for (int e = 0; e < 6; e++) {
            int nc = (e < 5) ? e + 1 : 0;
            const float* src = (e == 5) ? yb : ya;
            float* kout = (e < 5) ? kb + (size_t)(e + 1)*NS : kg;
            int mode = (e == 4) ? 1 : ((e == 5) ? 2 : 0);
            eval(src, nc, g_cf[e], g_ct[e], kout, mode, gev, partp);
            gev++;
        }
        wait_all(gev - 1);   // all tiles finished the err eval (partials at L3)
        float v = ld_sysf(&partp[tid]) + ld_sysf(&partp[tid + 256]);
        s_red[tid] = v;
        __syncthreads();
        for (int sft = 128; sft > 0; sft >>= 1) {
            if (tid < sft) s_red[tid] += s_red[tid + sft];
            __syncthreads();
        }
        float red0 = s_red[0];
        __syncthreads();
        float err_norm = sqrtf(red0 / (float)NS);
        float dtc = fminf(dt, 1.0f - t);
        bool adv = (err_norm <= 1.0f);
        if (adv) {
            t = t + dtc;
            float* tmp = ya; ya = yb; yb = tmp;   // y <- y5
            tmp = ka; ka = kg; kg = tmp;          // k1 <- k7 (FSAL)
        }
        float safe = fmaxf(err_norm, 1e-10f);
        float factor = fminf(fmaxf(0.9f*powf(safe, -0.2f), 0.2f), 10.0f);
        dt = dtc*factor;
    }

    // flush private interior rows of final y to L3, then publish + wait
    for (int tile = blockIdx.x; tile < 512; tile += nblk) {
        int b = tile >> 3, rg = tile & 7;
        if (tid < 128) {
            int lrow = tid >> 5;
            if (lrow == 1 || lrow == 2) {
                int px = rg*128 + tid;
                float* yp = ya + (((size_t)(b << 10) + px) << 3);
                float4 v0 = *(const float4*)yp;
                float4 v1 = *(const float4*)(yp + 4);
                st_sysf2(yp,     v0.x, v0.y);
                st_sysf2(yp + 2, v0.z, v0.w);
                st_sysf2(yp + 4, v1.x, v1.y);
                st_sysf2(yp + 6, v1.z, v1.w);
            }
        }
    }
    __syncthreads();
    for (int tile = blockIdx.x; tile < 512; tile += nblk)
        if (tid == 0)
            __hip_atomic_store(&flags[tile], gev, __ATOMIC_RELAXED,
                               __HIP_MEMORY_SCOPE_SYSTEM);
    wait_all(gev);

    // final linear head
    for (int bh = blockIdx.x; bh < 64; bh += nblk) {
        float* s_hred = (float*)s_pool;   // 10*256 floats overlay
        float acc[10];
        #pragma unroll
        for (int m = 0; m < 10; m++) acc[m] = 0.0f;
        for (int px = tid; px < 1024; px += 256) {
            const float* yp = ya + (((size_t)(bh << 10) + px) << 3);
            float yv[8];
            #pragma unroll
            for (int h = 0; h < 4; h++) {
                float2 v = ld_sysf2(yp + 2*h);
                yv[2*h] = v.x; yv[2*h+1] = v.y;
            }
            #pragma unroll
            for (int c = 0; c < 8; c++) {
                float v = yv[c];
                #pragma unroll
                for (int m = 0; m < 10; m++)
                    acc[m] = fmaf(v, wl[(size_t)m*8192 + (c << 10) + px], acc[m]);
            }
        }
        #pragma unroll
        for (int m = 0; m < 10; m++) s_hred[m*256 + tid] = acc[m];
        __syncthreads();
        for (int sft = 128; sft > 0; sft >>= 1) {
            if (tid < sft) {
                #pragma unroll
                for (int m = 0; m < 10; m++)
                    s_hred[m*256 + tid] += s_hred[m*256 + tid + sft];
            }
            __syncthreads();
        }
        if (tid < 10) out[bh*10 + tid] = s_hred[tid*256] + bl[tid];
        __syncthreads();
    }
}

// ---------------- host ----------------
extern "C" void kernel_launch(void* const* d_in, const int* in_sizes, int n_in,
                              void* d_out, int out_size, void* d_ws, size_t ws_size,
                              hipStream_t stream)
{
    const float* x  = (const float*)d_in[0];
    const float* w1 = (const float*)d_in[1];
    const float* b1 = (const float*)d_in[2];
    const float* w2 = (const float*)d_in[3];
    const float* b2 = (const float*)d_in[4];
    const float* w3 = (const float*)d_in[5];
    const float* b3 = (const float*)d_in[6];
    const float* wl = (const float*)d_in[7];
    const float* bl = (const float*)d_in[8];
    float* out = (float*)d_out;

    float* F = (float*)d_ws;
    float* part = F + OFF_PART;
    int*   flags = (int*)(F + OFF_FLAG);
    unsigned* cnt = (unsigned*)(F + OFF_CNT);
    float* tsum = F + OFF_TSUM;
    _Float16* w2p = (_Float16*)(F + OFF_W2P);
    float* y    = F + OFF_Y;
    float* y5   = F + OFF_Y5;
    float* kbp  = F + OFF_K;
    float* wpk  = F + OFF_WPK;

    k_init<<<NS/256, 256, 0, stream>>>(x, y, flags, cnt);
    k_prepack<<<144, 256, 0, stream>>>(w1, w2, w3, w2p, tsum, wpk);

    int maxb = 0;
    if (hipOccupancyMaxActiveBlocksPerMultiprocessor(&maxb,
            reinterpret_cast<const void*>(k_ode), 256, 0) != hipSuccess || maxb < 1)
        maxb = 1;
    int cus = 256;
    {
        int dev = 0;
        hipGetDevice(&dev);
        hipDeviceProp_t prop;
        if (hipGetDeviceProperties(&prop, dev) == hipSuccess && prop.multiProcessorCount > 0)
            cus = prop.multiProcessorCount;
    }
    long cap = (long)maxb * (long)cus;
    int gridn = (int)((cap < 512) ? cap : 512);
    if (gridn < 16) gridn = 16;

    k_ode<<<gridn, 256, 0, stream>>>(b1, b2, b3, w2p, tsum, wpk, wl, bl,
                                     y, y5, kbp, part, flags, out);
}

// Round 3
// 464.370 us; speedup vs baseline: 1.3480x; 1.0209x over previous
//
#include <hip/hip_runtime.h>
#include <math.h>

namespace {
constexpr int BN = 64;
constexpr int HW = 1024;
constexpr int NS = BN*8*HW;      // 524288

constexpr float C2f = 0.2f, C3f = 0.3f, C4f = 0.8f, C5f = (float)(8.0/9.0);
constexpr float A21 = 0.2f;
constexpr float A31 = (float)(3.0/40.0),  A32 = (float)(9.0/40.0);
constexpr float A41 = (float)(44.0/45.0), A42 = (float)(-56.0/15.0), A43 = (float)(32.0/9.0);
constexpr float A51 = (float)(19372.0/6561.0), A52 = (float)(-25360.0/2187.0),
                A53 = (float)(64448.0/6561.0), A54 = (float)(-212.0/729.0);
constexpr float A61 = (float)(9017.0/3168.0), A62 = (float)(-355.0/33.0),
                A63 = (float)(46732.0/5247.0), A64 = (float)(49.0/176.0),
                A65 = (float)(-5103.0/18656.0);
constexpr float B1c = (float)(35.0/384.0), B3c = (float)(500.0/1113.0),
                B4c = (float)(125.0/192.0), B5c = (float)(-2187.0/6784.0),
                B6c = (float)(11.0/84.0);
constexpr float E1c = (float)(71.0/57600.0), E3c = (float)(-71.0/16695.0),
                E4c = (float)(71.0/1920.0), E5c = (float)(-17253.0/339200.0),
                E6c = (float)(22.0/525.0),  E7c = (float)(-1.0/40.0);
constexpr float RTOL = 1e-3f, ATOL = 1e-3f;

// ws layout (floats / ints)
constexpr size_t OFF_PART = 0;        // 1024 floats (double-buffered by step parity)
constexpr size_t OFF_FLAG = 1024;     // 512 ints
constexpr size_t OFF_CNT  = 1536;     // 1 int (+pad) [unused, kept]
constexpr size_t OFF_TSUM = 1600;     // 576
constexpr size_t OFF_W2P  = 2176;     // 36864 halfs = 18432 floats
constexpr size_t OFF_Y    = 20608;    // y buffers px-major: [b][px][8]
constexpr size_t OFF_Y5   = OFF_Y  + (size_t)NS;
constexpr size_t OFF_K    = OFF_Y5 + (size_t)NS;   // 7*NS (k1..k7, px-major)
constexpr size_t OFF_WPK  = OFF_K + (size_t)7*NS;  // w1t(512) w10(64) w3t(512) w30(8)

// LDS strides (bytes). 264 = 66 dwords == 2 (mod 32), 136 = 34 dwords == 2 (mod 32):
// uint2 (b64) accesses tile the banks (2 lanes/bank = free per m136).
constexpr int ACT_STRIDE = 264;
constexpr int H2_STRIDE  = 136;
}

__constant__ float g_cf[6][5] = {
    {A21, 0, 0, 0, 0},
    {A31, A32, 0, 0, 0},
    {A41, A42, A43, 0, 0},
    {A51, A52, A53, A54, 0},
    {A61, A62, A63, A64, A65},
    {0, 0, 0, 0, 0}};
__constant__ float g_ct[6] = {C2f, C3f, C4f, C5f, 1.0f, 1.0f};

typedef _Float16 hfrag8 __attribute__((ext_vector_type(8)));
typedef float f32x16 __attribute__((ext_vector_type(16)));

union HU { hfrag8 h; unsigned u[4]; };

// ---- system-scope (L3-coherent) accessors ----
__device__ __forceinline__ float ld_sysf(const float* p) {
    return __hip_atomic_load(p, __ATOMIC_RELAXED, __HIP_MEMORY_SCOPE_SYSTEM);
}
__device__ __forceinline__ float2 ld_sysf2(const float* p) {
    union { unsigned long long u; float2 f; } c;
    c.u = __hip_atomic_load((const unsigned long long*)p, __ATOMIC_RELAXED,
                            __HIP_MEMORY_SCOPE_SYSTEM);
    return c.f;
}
__device__ __forceinline__ void st_sysf(float* p, float v) {
    __hip_atomic_store(p, v, __ATOMIC_RELAXED, __HIP_MEMORY_SCOPE_SYSTEM);
}
__device__ __forceinline__ void st_sysf2(float* p, float a, float b) {
    union { unsigned long long u; float2 f; } c;
    c.f = make_float2(a, b);
    __hip_atomic_store((unsigned long long*)p, c.u, __ATOMIC_RELAXED,
                       __HIP_MEMORY_SCOPE_SYSTEM);
}

// 8-float load/store with scope selected by row class (sys = boundary row)
__device__ __forceinline__ void ld8(const float* p, float* v, bool sys) {
    if (sys) {
        #pragma unroll
        for (int h = 0; h < 4; h++) {
            float2 t = ld_sysf2(p + 2*h);
            v[2*h] = t.x; v[2*h+1] = t.y;
        }
    } else {
        float4 a = *(const float4*)p;
        float4 b = *(const float4*)(p + 4);
        v[0]=a.x; v[1]=a.y; v[2]=a.z; v[3]=a.w;
        v[4]=b.x; v[5]=b.y; v[6]=b.z; v[7]=b.w;
    }
}
__device__ __forceinline__ void st8(float* p, const float* v, bool sys) {
    if (sys) {
        st_sysf2(p,     v[0], v[1]);
        st_sysf2(p + 2, v[2], v[3]);
        st_sysf2(p + 4, v[4], v[5]);
        st_sysf2(p + 6, v[6], v[7]);
    } else {
        *(float4*)p       = make_float4(v[0], v[1], v[2], v[3]);
        *(float4*)(p + 4) = make_float4(v[4], v[5], v[6], v[7]);
    }
}

// ---------------- init ----------------
__global__ __launch_bounds__(256)
void k_init(const float* __restrict__ x, float* __restrict__ y,
            int* __restrict__ flags, unsigned* __restrict__ cnt)
{
    int idx = blockIdx.x*256 + threadIdx.x;           // < NS
    int b = idx >> 13, px = (idx >> 3) & 1023, c = idx & 7;
    y[idx] = (c < 3) ? x[(size_t)(b*3 + c)*1024 + px] : 0.0f;
    if (idx < 512) flags[idx] = 0;
    if (idx == 600) *cnt = 0u;
}

// ---------------- prepack: w2 fp16 frag order + t-channel table + w1/w3 transposes ----------------
__global__ __launch_bounds__(256)
void k_prepack(const float* __restrict__ w1, const float* __restrict__ w2,
               const float* __restrict__ w3, _Float16* __restrict__ w2p,
               float* __restrict__ tsum, float* __restrict__ wpk)
{
    int gid = blockIdx.x*256 + threadIdx.x;
    if (gid < 36864) {
        int j    = gid & 7;
        int lane = (gid >> 3) & 63;
        int nt   = (gid >> 9) & 1;
        int ks   = (gid >> 10) & 3;
        int tap  = gid >> 12;            // 0..8
        int oc = nt*32 + (lane & 31);
        int ic = ks*16 + (lane >> 5)*8 + j;
        w2p[gid] = (_Float16)w2[oc*585 + (1 + ic)*9 + tap];
    }
    if (gid < 576) {
        int oc = gid & 63, combo = gid >> 6;       // 0..8
        int rcase = combo / 3, ccase = combo % 3;
        float s = 0.0f;
        for (int kh = 0; kh < 3; kh++) {
            if ((rcase == 1 && kh == 0) || (rcase == 2 && kh == 2)) continue;
            for (int kw = 0; kw < 3; kw++) {
                if ((ccase == 1 && kw == 0) || (ccase == 2 && kw == 2)) continue;
                s += w2[oc*585 + kh*3 + kw];
            }
        }
        tsum[gid] = s;
    }
    // w1t: wpk[c*64 + o] = w1[o*9 + 1 + c]
    if (gid < 512) wpk[gid] = w1[(gid & 63)*9 + 1 + (gid >> 6)];
    // w10[o]
    if (gid < 64)  wpk[512 + gid] = w1[gid*9];
    // w3t: wpk[576 + c*8 + o] = w3[o*65 + 1 + c]
    if (gid < 512) wpk[576 + gid] = w3[(gid & 7)*65 + 1 + (gid >> 3)];
    // w30[o]
    if (gid < 8)   wpk[1088 + gid] = w3[gid*65];
}

// ---------------- the whole ODE solve: one co-resident kernel ----------------
// R3: conv2 B-frags: load center (kw=1) only, derive kw=0/2 via DPP wave
// shifts with halo-zero injection (cuts conv2 LDS reads 72->16 per wave).
// Conflict-free LDS write strides (264/136). h2 in separate buffer
// (drops the P3->P4 barrier). Halo-column zero phase deleted.
__global__ void __launch_bounds__(256, 2)
k_ode(const float* __restrict__ b1, const float* __restrict__ b2,
      const float* __restrict__ b3, const _Float16* __restrict__ w2p,
      const float* __restrict__ tsumg, const float* __restrict__ wpk,
      const float* __restrict__ wl, const float* __restrict__ bl,
      float* __restrict__ ybuf, float* __restrict__ y5buf,
      float* __restrict__ kb, float* __restrict__ part,
      int* __restrict__ flags, float* __restrict__ out)
{
    __shared__ __align__(16) unsigned char s_pool[53600];   // act: 203 px * 264B
    __shared__ __align__(16) unsigned char s_h2[17408];     // h2: 128 px * 136B
    __shared__ __align__(16) _Float16 s_z[1552];   // 192 frags + zero slot @192
    __shared__ float s_tsum[576];
    __shared__ float s_b2v[64], s_b1v[64], s_w10v[64];
    __shared__ float s_w30v[8], s_b3v[8];
    __shared__ float s_red[256];

    const int tid = threadIdx.x;
    const int nblk = gridDim.x;
    const int lane = tid & 63;
    const int m32 = lane & 31, q2 = lane >> 5;
    const int rp = tid >> 7;          // row-pair for conv2
    const int np = (tid >> 6) & 1;    // oc-half for conv2
    const int wid = tid >> 6;         // wave id
    const bool lz32 = (lane == 32);
    const bool lz31 = (lane == 31);

    if (tid < 64) {
        s_b2v[tid] = b2[tid];
        s_b1v[tid] = b1[tid];
        s_w10v[tid] = wpk[512 + tid];
    }
    if (tid < 8) { s_w30v[tid] = wpk[1088 + tid]; s_b3v[tid] = b3[tid]; }
    for (int i = tid; i < 576; i += 256) s_tsum[i] = tsumg[i];
    if (tid < 8) s_z[192*8 + tid] = (_Float16)0.0f;   // zero frag slot
    __syncthreads();

    // resident weight fragments (A-operand layout: row=lane&31, k=q2*8+j)
    const int oct1 = wid >> 1;        // conv1 oc-tile for this wave
    hfrag8 w1f;
    #pragma unroll
    for (int j = 0; j < 8; j++)
        w1f[j] = q2 ? (_Float16)0.0f : (_Float16)wpk[j*64 + oct1*32 + m32];
    hfrag8 w3f[4];
    #pragma unroll
    for (int kst = 0; kst < 4; kst++)
        #pragma unroll
        for (int j = 0; j < 8; j++) {
            int ch = kst*16 + q2*8 + j;
            w3f[kst][j] = (m32 < 8) ? (_Float16)wpk[576 + ch*8 + m32]
                                    : (_Float16)0.0f;
        }

    float t = 0.0f, dt = 0.1f;
    float* ya = ybuf; float* yb = y5buf;
    float* ka = kb;  float* kg = kb + 6*(size_t)NS;

    auto wait_all = [&](int target) {
        for (;;) {
            bool ok = (__hip_atomic_load(&flags[tid], __ATOMIC_RELAXED,
                           __HIP_MEMORY_SCOPE_SYSTEM) >= target)
                   && (__hip_atomic_load(&flags[tid + 256], __ATOMIC_RELAXED,
                           __HIP_MEMORY_SCOPE_SYSTEM) >= target);
            if (__syncthreads_and((int)ok)) break;
            __builtin_amdgcn_s_sleep(2);
        }
    };

    auto eval = [&](const float* src, int nc, const float* cf, float ctv,
                    float* kout, int mode, int gev, float* partp) {
        float dtc = fminf(dt, 1.0f - t);
        float ts  = t + ctv*dtc;

        for (int tile = blockIdx.x; tile < 512; tile += nblk) {
            int b = tile >> 3, rg = tile & 7;

            // P2a) z-combine -> fp16 frags in s_z (wave-row map {2,3|1,4|0,5})
            if (tid < 192) {
                int w = tid >> 5;
                int lr = (0x504132 >> (4*w)) & 7;
                int col = tid & 31;
                int r = rg*4 - 1 + lr;
                bool sysrow = (lr < 2) | (lr > 3);
                if (gev > 1 && w >= 4) {
                    const int* fp = (lr == 0) ? &flags[tile-1] : &flags[tile+1];
                    bool need = (lr == 0) ? (rg > 0) : (rg < 7);
                    while (need && __hip_atomic_load(fp, __ATOMIC_RELAXED,
                                                     __HIP_MEMORY_SCOPE_SYSTEM) < gev-1)
                        __builtin_amdgcn_s_sleep(1);
                }
                union { _Float16 h[8]; uint4 u; } pz;
                if ((unsigned)r < 32u) {
                    int px = (r << 5) + col;
                    size_t pb8 = ((size_t)(b << 10) + px) << 3;
                    float kv[5][8], sv[8];
                    if (sysrow) {
                        #pragma unroll
                        for (int j = 0; j < 5; j++) if (j < nc) {
                            const float* kp = (j == 0 ? ka : kb + (size_t)j*NS) + pb8;
                            #pragma unroll
                            for (int h = 0; h < 4; h++) {
                                float2 t2 = ld_sysf2(kp + 2*h);
                                kv[j][2*h] = t2.x; kv[j][2*h+1] = t2.y;
                            }
                        }
                        #pragma unroll
                        for (int h = 0; h < 4; h++) {
                            float2 t2 = ld_sysf2(src + pb8 + 2*h);
                            sv[2*h] = t2.x; sv[2*h+1] = t2.y;
                        }
                    } else {
                        #pragma unroll
                        for (int j = 0; j < 5; j++) if (j < nc) {
                            const float* kp = (j == 0 ? ka : kb + (size_t)j*NS) + pb8;
                            float4 a4 = *(const float4*)kp;
                            float4 b4 = *(const float4*)(kp + 4);
                            kv[j][0]=a4.x; kv[j][1]=a4.y; kv[j][2]=a4.z; kv[j][3]=a4.w;
                            kv[j][4]=b4.x; kv[j][5]=b4.y; kv[j][6]=b4.z; kv[j][7]=b4.w;
                        }
                        float4 a4 = *(const float4*)(src + pb8);
                        float4 b4 = *(const float4*)(src + pb8 + 4);
                        sv[0]=a4.x; sv[1]=a4.y; sv[2]=a4.z; sv[3]=a4.w;
                        sv[4]=b4.x; sv[5]=b4.y; sv[6]=b4.z; sv[7]=b4.w;
                    }
                    float s[8] = {0,0,0,0,0,0,0,0};
                    #pragma unroll
                    for (int j = 0; j < 5; j++) if (j < nc) {
                        float a = cf[j];
                        #pragma unroll
                        for (int c = 0; c < 8; c++) s[c] = fmaf(a, kv[j][c], s[c]);
                    }
                    #pragma unroll
                    for (int c = 0; c < 8; c++)
                        pz.h[c] = (_Float16)(sv[c] + dtc*s[c]);
                } else {
                    pz.u = make_uint4(0u,0u,0u,0u);
                }
                *(uint4*)(s_z + (size_t)(lr*32 + col)*8) = pz.u;
            }
            __syncthreads();

            // P2b) conv1 via MFMA: 6 rows x 2 oc-tiles over 4 waves
            {
                int pgbase = (wid & 1)*3;
                #pragma unroll
                for (int i = 0; i < 3; i++) {
                    int pxg = pgbase + i;
                    int r = rg*4 - 1 + pxg;
                    bool valid = ((unsigned)r < 32u);
                    const _Float16* zp = s_z + (q2 ? (size_t)192*8
                                                   : (size_t)(pxg*32 + m32)*8);
                    hfrag8 bz = *(const hfrag8*)zp;
                    f32x16 a1 = (f32x16)(0.0f);
                    a1 = __builtin_amdgcn_mfma_f32_32x32x16_f16(w1f, bz, a1, 0,0,0);
                    unsigned words[8];
                    #pragma unroll
                    for (int pr = 0; pr < 8; pr++) {
                        int r0 = 2*pr;
                        int oc0 = oct1*32 + (r0&3) + 8*(r0>>2) + 4*q2;
                        float v0 = valid ? fmaxf(a1[r0]   + ts*s_w10v[oc0]
                                                 + s_b1v[oc0],   0.0f) : 0.0f;
                        float v1 = valid ? fmaxf(a1[r0+1] + ts*s_w10v[oc0+1]
                                                 + s_b1v[oc0+1], 0.0f) : 0.0f;
                        union { _Float16 h[2]; unsigned u; } pk;
                        pk.h[0] = (_Float16)v0; pk.h[1] = (_Float16)v1;
                        words[pr] = pk.u;
                    }
                    unsigned char* basep = s_pool
                        + (size_t)(pxg*34 + m32 + 1)*ACT_STRIDE + oct1*64 + q2*8;
                    #pragma unroll
                    for (int wq = 0; wq < 4; wq++)
                        *(uint2*)(basep + wq*16) =
                            make_uint2(words[2*wq], words[2*wq+1]);
                }
            }
            __syncthreads();

            // P3) conv2: center-frag loads + DPP-derived kw shifts
            f32x16 acc2[2];
            acc2[0] = (f32x16)(0.0f);
            acc2[1] = (f32x16)(0.0f);
            {
                const unsigned char* actb = (const unsigned char*)s_pool;
                #pragma unroll 1
                for (int ks = 0; ks < 4; ks++) {
                    HU fc[4], d0[4], d2[4];
                    #pragma unroll
                    for (int l = 0; l < 4; l++) {
                        const unsigned char* p = actb
                            + (size_t)((rp*2 + l)*34 + m32 + 1)*ACT_STRIDE
                            + ks*32 + q2*16;
                        *(uint2*)&fc[l].u[0] = *(const uint2*)p;
                        *(uint2*)&fc[l].u[2] = *(const uint2*)(p + 8);
                    }
                    #pragma unroll
                    for (int l = 0; l < 4; l++) {
                        #pragma unroll
                        for (int i = 0; i < 4; i++) {
                            unsigned s0 = (unsigned)__builtin_amdgcn_update_dpp(
                                0, (int)fc[l].u[i], 0x138, 0xF, 0xF, true); // wave_shr:1
                            d0[l].u[i] = lz32 ? 0u : s0;
                            unsigned s2 = (unsigned)__builtin_amdgcn_update_dpp(
                                0, (int)fc[l].u[i], 0x130, 0xF, 0xF, true); // wave_shl:1
                            d2[l].u[i] = lz31 ? 0u : s2;
                        }
                    }
                    #pragma unroll
                    for (int kh = 0; kh < 3; kh++) {
                        #pragma unroll
                        for (int kw = 0; kw < 3; kw++) {
                            int tap = kh*3 + kw;
                            hfrag8 aw = *(const hfrag8*)
                                (w2p + (size_t)((tap*4 + ks)*2 + np)*512 + lane*8);
                            #pragma unroll
                            for (int ri = 0; ri < 2; ri++) {
                                int l = ri + kh;
                                hfrag8 bf = (kw == 0) ? d0[l].h
                                          : ((kw == 1) ? fc[l].h : d2[l].h);
                                acc2[ri] = __builtin_amdgcn_mfma_f32_32x32x16_f16(
                                    aw, bf, acc2[ri], 0, 0, 0);
                            }
                        }
                    }
                }
            }
            // no barrier: P4 writes s_h2 (separate buffer), register-only inputs

            // P4) epilogue: t-channel + bias + relu -> h2 px-major fp16, stride 136B
            {
                int ccase = (m32 == 0) ? 1 : ((m32 == 31) ? 2 : 0);
                #pragma unroll
                for (int ri = 0; ri < 2; ri++) {
                    int pg = rp*2 + ri;
                    int r_out = rg*4 + pg;
                    int rcase = (r_out == 0) ? 1 : ((r_out == 31) ? 2 : 0);
                    const float* tsb = &s_tsum[(rcase*3 + ccase)*64];
                    int px = pg*32 + m32;
                    unsigned words[8];
                    #pragma unroll
                    for (int pr = 0; pr < 8; pr++) {
                        int r0 = 2*pr;
                        int oc0 = np*32 + (r0&3) + 8*(r0>>2) + 4*q2;
                        float v0 = fmaxf(acc2[ri][r0]   + ts*tsb[oc0]
                                         + s_b2v[oc0],   0.0f);
                        float v1 = fmaxf(acc2[ri][r0+1] + ts*tsb[oc0+1]
                                         + s_b2v[oc0+1], 0.0f);
                        union { _Float16 h[2]; unsigned u; } pk;
                        pk.h[0] = (_Float16)v0; pk.h[1] = (_Float16)v1;
                        words[pr] = pk.u;
                    }
                    unsigned char* basep = s_h2 + (size_t)px*H2_STRIDE
                                           + np*64 + q2*8;
                    #pragma unroll
                    for (int wq = 0; wq < 4; wq++)
                        *(uint2*)(basep + wq*16) =
                            make_uint2(words[2*wq], words[2*wq+1]);
                }
            }
            __syncthreads();

            // P5) conv3 via MFMA (K=64 in 4 steps) + mode epilogues
            {
                f32x16 a3a = (f32x16)(0.0f);
                const unsigned char* hb = (const unsigned char*)s_h2;
                #pragma unroll
                for (int kst = 0; kst < 4; kst++) {
                    HU f;
                    const unsigned char* p = hb
                        + (size_t)(wid*32 + m32)*H2_STRIDE + kst*32 + q2*16;
                    *(uint2*)&f.u[0] = *(const uint2*)p;
                    *(uint2*)&f.u[2] = *(const uint2*)(p + 8);
                    a3a = __builtin_amdgcn_mfma_f32_32x32x16_f16(
                        w3f[kst], f.h, a3a, 0, 0, 0);
                }
                // gather the other oc-half from partner lane (lane ^ 32)
                float a3[8];
                #pragma unroll
                for (int r = 0; r < 4; r++) {
                    float own = a3a[r];
                    float oth = __shfl(own, lane ^ 32, 64);
                    a3[r]     = q2 ? oth : own;
                    a3[4 + r] = q2 ? own : oth;
                }
                float ls = 0.0f;
                if (q2 == 0) {
                    #pragma unroll
                    for (int c = 0; c < 8; c++)
                        a3[c] += fmaf(ts, s_w30v[c], s_b3v[c]);
                    bool sysrow = (wid == 0) | (wid == 3);
                    int px = rg*128 + wid*32 + m32;
                    size_t pb8 = ((size_t)(b << 10) + px) << 3;
                    st8(kout + pb8, a3, sysrow);
                    if (mode == 1) {
                        float kv1[8], kv3[8], kv4[8], kv5[8], yv[8], r8[8];
                        ld8(ka + pb8, kv1, sysrow);
                        ld8(kb + 2*(size_t)NS + pb8, kv3, sysrow);
                        ld8(kb + 3*(size_t)NS + pb8, kv4, sysrow);
                        ld8(kb + 4*(size_t)NS + pb8, kv5, sysrow);
                        ld8(ya + pb8, yv, sysrow);
                        #pragma unroll
                        for (int c = 0; c < 8; c++)
                            r8[c] = yv[c] + dtc*(B1c*kv1[c] + B3c*kv3[c]
                                    + B4c*kv4[c] + B5c*kv5[c] + B6c*a3[c]);
                        st8(yb + pb8, r8, sysrow);
                    } else if (mode == 2) {
                        float kv1[8], kv3[8], kv4[8], kv5[8], kv6[8], yv[8], y5v[8];
                        ld8(ka + pb8, kv1, sysrow);
                        ld8(kb + 2*(size_t)NS + pb8, kv3, sysrow);
                        ld8(kb + 3*(size_t)NS + pb8, kv4, sysrow);
                        ld8(kb + 4*(size_t)NS + pb8, kv5, sysrow);
                        ld8(kb + 5*(size_t)NS + pb8, kv6, sysrow);
                        ld8(ya + pb8, yv, sysrow);
                        ld8(yb + pb8, y5v, sysrow);
                        #pragma unroll
                        for (int c = 0; c < 8; c++) {
                            float e = dtc*(E1c*kv1[c] + E3c*kv3[c] + E4c*kv4[c]
                                           + E5c*kv5[c] + E6c*kv6[c] + E7c*a3[c]);
                            float tol = ATOL + RTOL*fmaxf(fabsf(yv[c]), fabsf(y5v[c]));
                            float rr = e / tol;
                            ls += rr*rr;
                        }
                    }
                }
                if (mode == 2) {
                    s_red[tid] = ls;
                    __syncthreads();
                    for (int sft = 128; sft > 0; sft >>= 1) {
                        if (tid < sft) s_red[tid] += s_red[tid + sft];
                        __syncthreads();
                    }
                    if (tid == 0) st_sysf(&partp[tile], s_red[0]);
                }
            }
            // release: syncthreads drains vmcnt (sys stores at L3), then flag
            __syncthreads();
            if (tid == 0)
                __hip_atomic_store(&flags[tile], gev, __ATOMIC_RELAXED,
                                   __HIP_MEMORY_SCOPE_SYSTEM);
        }
    };

    int gev = 1;
    eval(ya, 0, g_cf[5], 0.0f, ka, 0, gev, part);   // k1 = f(t0, y0)
    gev++;

    for (int st = 0; st < 24; st++) {
        if (t >= 1.0f - 1e-7f) break;
        float* partp = part + (size_t)(st & 1)*512;
        for (int e = 0; e < 6; e++) {
            int nc = (e < 5) ? e + 1 : 0;
            const float* src = (e == 5) ? yb : ya;
            float* kout = (e < 5) ? kb + (size_t)(e + 1)*NS : kg;
            int mode = (e == 4) ? 1 : ((e == 5) ? 2 : 0);
            eval(src, nc, g_cf[e], g_ct[e], kout, mode, gev, partp);
            gev++;
        }
        wait_all(gev - 1);   // all tiles finished the err eval (partials at L3)
        float v = ld_sysf(&partp[tid]) + ld_sysf(&partp[tid + 256]);
        s_red[tid] = v;
        __syncthreads();
        for (int sft = 128; sft > 0; sft >>= 1) {
            if (tid < sft) s_red[tid] += s_red[tid + sft];
            __syncthreads();
        }
        float red0 = s_red[0];
        __syncthreads();
        float err_norm = sqrtf(red0 / (float)NS);
        float dtc = fminf(dt, 1.0f - t);
        bool adv = (err_norm <= 1.0f);
        if (adv) {
            t = t + dtc;
            float* tmp = ya; ya = yb; yb = tmp;   // y <- y5
            tmp = ka; ka = kg; kg = tmp;          // k1 <- k7 (FSAL)
        }
        float safe = fmaxf(err_norm, 1e-10f);
        float factor = fminf(fmaxf(0.9f*powf(safe, -0.2f), 0.2f), 10.0f);
        dt = dtc*factor;
    }

    // flush private interior rows of final y to L3, then publish + wait
    for (int tile = blockIdx.x; tile < 512; tile += nblk) {
        int b = tile >> 3, rg = tile & 7;
        if (tid < 128) {
            int lrow = tid >> 5;
            if (lrow == 1 || lrow == 2) {
                int px = rg*128 + tid;
                float* yp = ya + (((size_t)(b << 10) + px) << 3);
                float4 v0 = *(const float4*)yp;
                float4 v1 = *(const float4*)(yp + 4);
                st_sysf2(yp,     v0.x, v0.y);
                st_sysf2(yp + 2, v0.z, v0.w);
                st_sysf2(yp + 4, v1.x, v1.y);
                st_sysf2(yp + 6, v1.z, v1.w);
            }
        }
    }
    __syncthreads();
    for (int tile = blockIdx.x; tile < 512; tile += nblk)
        if (tid == 0)
            __hip_atomic_store(&flags[tile], gev, __ATOMIC_RELAXED,
                               __HIP_MEMORY_SCOPE_SYSTEM);
    wait_all(gev);

    // final linear head
    for (int bh = blockIdx.x; bh < 64; bh += nblk) {
        float* s_hred = (float*)s_pool;   // 10*256 floats overlay
        float acc[10];
        #pragma unroll
        for (int m = 0; m < 10; m++) acc[m] = 0.0f;
        for (int px = tid; px < 1024; px += 256) {
            const float* yp = ya + (((size_t)(bh << 10) + px) << 3);
            float yv[8];
            #pragma unroll
            for (int h = 0; h < 4; h++) {
                float2 v = ld_sysf2(yp + 2*h);
                yv[2*h] = v.x; yv[2*h+1] = v.y;
            }
            #pragma unroll
            for (int c = 0; c < 8; c++) {
                float v = yv[c];
                #pragma unroll
                for (int m = 0; m < 10; m++)
                    acc[m] = fmaf(v, wl[(size_t)m*8192 + (c << 10) + px], acc[m]);
            }
        }
        #pragma unroll
        for (int m = 0; m < 10; m++) s_hred[m*256 + tid] = acc[m];
        __syncthreads();
        for (int sft = 128; sft > 0; sft >>= 1) {
            if (tid < sft) {
                #pragma unroll
                for (int m = 0; m < 10; m++)
                    s_hred[m*256 + tid] += s_hred[m*256 + tid + sft];
            }
            __syncthreads();
        }
        if (tid < 10) out[bh*10 + tid] = s_hred[tid*256] + bl[tid];
        __syncthreads();
    }
}

// ---------------- host ----------------
extern "C" void kernel_launch(void* const* d_in, const int* in_sizes, int n_in,
                              void* d_out, int out_size, void* d_ws, size_t ws_size,
                              hipStream_t stream)
{
    const float* x  = (const float*)d_in[0];
    const float* w1 = (const float*)d_in[1];
    const float* b1 = (const float*)d_in[2];
    const float* w2 = (const float*)d_in[3];
    const float* b2 = (const float*)d_in[4];
    const float* w3 = (const float*)d_in[5];
    const float* b3 = (const float*)d_in[6];
    const float* wl = (const float*)d_in[7];
    const float* bl = (const float*)d_in[8];
    float* out = (float*)d_out;

    float* F = (float*)d_ws;
    float* part = F + OFF_PART;
    int*   flags = (int*)(F + OFF_FLAG);
    unsigned* cnt = (unsigned*)(F + OFF_CNT);
    float* tsum = F + OFF_TSUM;
    _Float16* w2p = (_Float16*)(F + OFF_W2P);
    float* y    = F + OFF_Y;
    float* y5   = F + OFF_Y5;
    float* kbp  = F + OFF_K;
    float* wpk  = F + OFF_WPK;

    k_init<<<NS/256, 256, 0, stream>>>(x, y, flags, cnt);
    k_prepack<<<144, 256, 0, stream>>>(w1, w2, w3, w2p, tsum, wpk);

    int maxb = 0;
    if (hipOccupancyMaxActiveBlocksPerMultiprocessor(&maxb,
            reinterpret_cast<const void*>(k_ode), 256, 0) != hipSuccess || maxb < 1)
        maxb = 1;
    int cus = 256;
    {
        int dev = 0;
        hipGetDevice(&dev);
        hipDeviceProp_t prop;
        if (hipGetDeviceProperties(&prop, dev) == hipSuccess && prop.multiProcessorCount > 0)
            cus = prop.multiProcessorCount;
    }
    long cap = (long)maxb * (long)cus;
    int gridn = (int)((cap < 512) ? cap : 512);
    if (gridn < 16) gridn = 16;

    k_ode<<<gridn, 256, 0, stream>>>(b1, b2, b3, w2p, tsum, wpk, wl, bl,
                                     y, y5, kbp, part, flags, out);
}

// Round 4
// 407.758 us; speedup vs baseline: 1.5351x; 1.1388x over previous
//
#include <hip/hip_runtime.h>
#include <math.h>

namespace {
constexpr int BN = 64;
constexpr int HW = 1024;
constexpr int NS = BN*8*HW;      // 524288

constexpr float C2f = 0.2f, C3f = 0.3f, C4f = 0.8f, C5f = (float)(8.0/9.0);
constexpr float A21 = 0.2f;
constexpr float A31 = (float)(3.0/40.0),  A32 = (float)(9.0/40.0);
constexpr float A41 = (float)(44.0/45.0), A42 = (float)(-56.0/15.0), A43 = (float)(32.0/9.0);
constexpr float A51 = (float)(19372.0/6561.0), A52 = (float)(-25360.0/2187.0),
                A53 = (float)(64448.0/6561.0), A54 = (float)(-212.0/729.0);
constexpr float A61 = (float)(9017.0/3168.0), A62 = (float)(-355.0/33.0),
                A63 = (float)(46732.0/5247.0), A64 = (float)(49.0/176.0),
                A65 = (float)(-5103.0/18656.0);
constexpr float B1c = (float)(35.0/384.0), B3c = (float)(500.0/1113.0),
                B4c = (float)(125.0/192.0), B5c = (float)(-2187.0/6784.0),
                B6c = (float)(11.0/84.0);
constexpr float E1c = (float)(71.0/57600.0), E3c = (float)(-71.0/16695.0),
                E4c = (float)(71.0/1920.0), E5c = (float)(-17253.0/339200.0),
                E6c = (float)(22.0/525.0),  E7c = (float)(-1.0/40.0);
constexpr float RTOL = 1e-3f, ATOL = 1e-3f;

// ws layout (floats / ints)
constexpr size_t OFF_PART = 0;        // 1024 floats (double-buffered by step parity)
constexpr size_t OFF_FLAG = 1024;     // 512 ints (tile fully done; step gate)
constexpr size_t OFF_CNT  = 1536;     // unused, kept
constexpr size_t OFF_TSUM = 1600;     // 576
constexpr size_t OFF_W2P  = 2176;     // 36864 halfs = 18432 floats
constexpr size_t OFF_Y    = 20608;    // y buffers px-major: [b][px][8]
constexpr size_t OFF_Y5   = OFF_Y  + (size_t)NS;
constexpr size_t OFF_K    = OFF_Y5 + (size_t)NS;   // 7*NS (k1..k7, px-major)
constexpr size_t OFF_WPK  = OFF_K + (size_t)7*NS;  // w1t(512) w10(64) w3t(512) w30(8)
constexpr size_t OFF_FT   = OFF_WPK + 1152;        // 512 ints: top-row ready
constexpr size_t OFF_FB   = OFF_FT + 512;          // 512 ints: bottom-row ready

// LDS strides (bytes), both == 4 dwords (mod 32): b128 ops tile banks (R0-style).
constexpr int ACT_STRIDE = 272;   // 192 px rows (6x32), 128B payload
constexpr int H2_STRIDE  = 144;   // 128 px rows, 128B payload
}

__constant__ float g_cf[6][5] = {
    {A21, 0, 0, 0, 0},
    {A31, A32, 0, 0, 0},
    {A41, A42, A43, 0, 0},
    {A51, A52, A53, A54, 0},
    {A61, A62, A63, A64, A65},
    {0, 0, 0, 0, 0}};
__constant__ float g_ct[6] = {C2f, C3f, C4f, C5f, 1.0f, 1.0f};

typedef _Float16 hfrag8 __attribute__((ext_vector_type(8)));
typedef float f32x16 __attribute__((ext_vector_type(16)));

union HU { hfrag8 h; unsigned u[4]; uint4 v; };

// ---- system-scope (L3-coherent) accessors ----
__device__ __forceinline__ float ld_sysf(const float* p) {
    return __hip_atomic_load(p, __ATOMIC_RELAXED, __HIP_MEMORY_SCOPE_SYSTEM);
}
__device__ __forceinline__ float2 ld_sysf2(const float* p) {
    union { unsigned long long u; float2 f; } c;
    c.u = __hip_atomic_load((const unsigned long long*)p, __ATOMIC_RELAXED,
                            __HIP_MEMORY_SCOPE_SYSTEM);
    return c.f;
}
__device__ __forceinline__ void st_sysf(float* p, float v) {
    __hip_atomic_store(p, v, __ATOMIC_RELAXED, __HIP_MEMORY_SCOPE_SYSTEM);
}
__device__ __forceinline__ void st_sysf2(float* p, float a, float b) {
    union { unsigned long long u; float2 f; } c;
    c.f = make_float2(a, b);
    __hip_atomic_store((unsigned long long*)p, c.u, __ATOMIC_RELAXED,
                       __HIP_MEMORY_SCOPE_SYSTEM);
}

// 8-float load/store with scope selected by row class (sys = boundary row)
__device__ __forceinline__ void ld8(const float* p, float* v, bool sys) {
    if (sys) {
        #pragma unroll
        for (int h = 0; h < 4; h++) {
            float2 t = ld_sysf2(p + 2*h);
            v[2*h] = t.x; v[2*h+1] = t.y;
        }
    } else {
        float4 a = *(const float4*)p;
        float4 b = *(const float4*)(p + 4);
        v[0]=a.x; v[1]=a.y; v[2]=a.z; v[3]=a.w;
        v[4]=b.x; v[5]=b.y; v[6]=b.z; v[7]=b.w;
    }
}
__device__ __forceinline__ void st8(float* p, const float* v, bool sys) {
    if (sys) {
        st_sysf2(p,     v[0], v[1]);
        st_sysf2(p + 2, v[2], v[3]);
        st_sysf2(p + 4, v[4], v[5]);
        st_sysf2(p + 6, v[6], v[7]);
    } else {
        *(float4*)p       = make_float4(v[0], v[1], v[2], v[3]);
        *(float4*)(p + 4) = make_float4(v[4], v[5], v[6], v[7]);
    }
}

// ---------------- init ----------------
__global__ __launch_bounds__(256)
void k_init(const float* __restrict__ x, float* __restrict__ y,
            int* __restrict__ flags, int* __restrict__ flagT,
            int* __restrict__ flagB)
{
    int idx = blockIdx.x*256 + threadIdx.x;           // < NS
    int b = idx >> 13, px = (idx >> 3) & 1023, c = idx & 7;
    y[idx] = (c < 3) ? x[(size_t)(b*3 + c)*1024 + px] : 0.0f;
    if (idx < 512) { flags[idx] = 0; flagT[idx] = 0; flagB[idx] = 0; }
}

// ---------------- prepack ----------------
// channel permutation pi(ch) = oct*32 + q2*16 + r  (MFMA C-reg order) so conv
// epilogues write 32B-contiguous chunks. w2p/w3 consume with inverse perm.
__global__ __launch_bounds__(256)
void k_prepack(const float* __restrict__ w1, const float* __restrict__ w2,
               const float* __restrict__ w3, _Float16* __restrict__ w2p,
               float* __restrict__ tsum, float* __restrict__ wpk)
{
    int gid = blockIdx.x*256 + threadIdx.x;
    if (gid < 36864) {
        int j    = gid & 7;
        int lane = (gid >> 3) & 63;
        int nt   = (gid >> 9) & 1;
        int ks   = (gid >> 10) & 3;
        int tap  = gid >> 12;            // 0..8
        int oc = nt*32 + (lane & 31);
        int kpos = ks*16 + (lane >> 5)*8 + j;
        int oct = kpos >> 5, q2b = (kpos >> 4) & 1, rr = kpos & 15;
        int ic = oct*32 + (rr & 3) + (q2b << 2) + ((rr >> 2) << 3);  // inv-pi
        w2p[gid] = (_Float16)w2[oc*585 + (1 + ic)*9 + tap];
    }
    if (gid < 576) {
        int oc = gid & 63, combo = gid >> 6;       // 0..8
        int rcase = combo / 3, ccase = combo % 3;
        float s = 0.0f;
        for (int kh = 0; kh < 3; kh++) {
            if ((rcase == 1 && kh == 0) || (rcase == 2 && kh == 2)) continue;
            for (int kw = 0; kw < 3; kw++) {
                if ((ccase == 1 && kw == 0) || (ccase == 2 && kw == 2)) continue;
                s += w2[oc*585 + kh*3 + kw];
            }
        }
        tsum[gid] = s;
    }
    // w1t: wpk[c*64 + o] = w1[o*9 + 1 + c]
    if (gid < 512) wpk[gid] = w1[(gid & 63)*9 + 1 + (gid >> 6)];
    // w10[o]
    if (gid < 64)  wpk[512 + gid] = w1[gid*9];
    // w3t: wpk[576 + c*8 + o] = w3[o*65 + 1 + c]
    if (gid < 512) wpk[576 + gid] = w3[(gid & 7)*65 + 1 + (gid >> 3)];
    // w30[o]
    if (gid < 8)   wpk[1088 + gid] = w3[gid*65];
}

// ---------------- the whole ODE solve ----------------
// R4: conv1 fully in registers (z = B-frag directly; lo/hi masked w1 A-frags);
// wave-aligned k handoff (wave stores row it reloads) -> end-of-eval barrier
// deleted (modes 0/1); per-wave early flagT/flagB release after vmcnt drain;
// pi-permuted act/h2 channel layout -> all LDS traffic b128 conflict-free.
__global__ void __launch_bounds__(256, 2)
k_ode(const float* __restrict__ b1, const float* __restrict__ b2,
      const float* __restrict__ b3, const _Float16* __restrict__ w2p,
      const float* __restrict__ tsumg, const float* __restrict__ wpk,
      const float* __restrict__ wl, const float* __restrict__ bl,
      float* __restrict__ ybuf, float* __restrict__ y5buf,
      float* __restrict__ kb, float* __restrict__ part,
      int* __restrict__ flags, int* __restrict__ flagT,
      int* __restrict__ flagB, float* __restrict__ out)
{
    __shared__ __align__(16) unsigned char s_pool[192*ACT_STRIDE]; // 52224
    __shared__ __align__(16) unsigned char s_h2[128*H2_STRIDE];    // 18432
    __shared__ float s_tsum[576];
    __shared__ float s_b2v[64], s_b1v[64], s_w10v[64];
    __shared__ float s_w30v[8], s_b3v[8];
    __shared__ float s_red[256];

    const int tid = threadIdx.x;
    const int nblk = gridDim.x;
    const int lane = tid & 63;
    const int m32 = lane & 31, q2 = lane >> 5;
    const int rp = tid >> 7;          // row-pair for conv2
    const int np = (tid >> 6) & 1;    // oc-half for conv2
    const int wid = tid >> 6;         // wave id
    const bool lz32 = (lane == 32);
    const bool lz31 = (lane == 31);

    if (tid < 64) {
        s_b2v[tid] = b2[tid];
        s_b1v[tid] = b1[tid];
        s_w10v[tid] = wpk[512 + tid];
    }
    if (tid < 8) { s_w30v[tid] = wpk[1088 + tid]; s_b3v[tid] = b3[tid]; }
    for (int i = tid; i < 576; i += 256) s_tsum[i] = tsumg[i];
    __syncthreads();

    // resident conv1 A-frags: lo (k=0..7 live) and hi (k=8..15 live)
    hfrag8 w1lo[2], w1hi[2];
    #pragma unroll
    for (int oct = 0; oct < 2; oct++)
        #pragma unroll
        for (int j = 0; j < 8; j++) {
            _Float16 wv = (_Float16)wpk[j*64 + oct*32 + m32];
            w1lo[oct][j] = q2 ? (_Float16)0.0f : wv;
            w1hi[oct][j] = q2 ? wv : (_Float16)0.0f;
        }
    // resident conv3 A-frags (channel positions permuted by inv-pi)
    hfrag8 w3f[4];
    #pragma unroll
    for (int kst = 0; kst < 4; kst++)
        #pragma unroll
        for (int j = 0; j < 8; j++) {
            int kpos = kst*16 + q2*8 + j;
            int oct = kpos >> 5, q2b = (kpos >> 4) & 1, rr = kpos & 15;
            int ch = oct*32 + (rr & 3) + (q2b << 2) + ((rr >> 2) << 3);
            w3f[kst][j] = (m32 < 8) ? (_Float16)wpk[576 + ch*8 + m32]
                                    : (_Float16)0.0f;
        }

    float t = 0.0f, dt = 0.1f;
    float* ya = ybuf; float* yb = y5buf;
    float* ka = kb;  float* kg = kb + 6*(size_t)NS;

    auto wait_all = [&](int target) {
        for (;;) {
            bool ok = (__hip_atomic_load(&flags[tid], __ATOMIC_RELAXED,
                           __HIP_MEMORY_SCOPE_SYSTEM) >= target)
                   && (__hip_atomic_load(&flags[tid + 256], __ATOMIC_RELAXED,
                           __HIP_MEMORY_SCOPE_SYSTEM) >= target);
            if (__syncthreads_and((int)ok)) break;
            __builtin_amdgcn_s_sleep(2);
        }
    };

    auto eval = [&](const float* src, int nc, const float* cf, float ctv,
                    float* kout, int mode, int gev, float* partp) {
        float dtc = fminf(dt, 1.0f - t);
        float ts  = t + ctv*dtc;

        for (int tile = blockIdx.x; tile < 512; tile += nblk) {
            int b = tile >> 3, rg = tile & 7;

            // ---- z-combine into registers (per-lane row) ----
            auto zload = [&](int lr) {
                HU pz; pz.v = make_uint4(0u,0u,0u,0u);
                int r = rg*4 - 1 + lr;
                if ((unsigned)lr < 6u && (unsigned)r < 32u) {
                    bool sysrow = (lr < 2) | (lr > 3);
                    int px = (r << 5) + m32;
                    size_t pb8 = ((size_t)(b << 10) + px) << 3;
                    float kv[5][8], sv[8];
                    if (sysrow) {
                        #pragma unroll
                        for (int j = 0; j < 5; j++) if (j < nc) {
                            const float* kp = (j == 0 ? ka : kb + (size_t)j*NS) + pb8;
                            #pragma unroll
                            for (int h = 0; h < 4; h++) {
                                float2 t2 = ld_sysf2(kp + 2*h);
                                kv[j][2*h] = t2.x; kv[j][2*h+1] = t2.y;
                            }
                        }
                        #pragma unroll
                        for (int h = 0; h < 4; h++) {
                            float2 t2 = ld_sysf2(src + pb8 + 2*h);
                            sv[2*h] = t2.x; sv[2*h+1] = t2.y;
                        }
                    } else {
                        #pragma unroll
                        for (int j = 0; j < 5; j++) if (j < nc) {
                            const float* kp = (j == 0 ? ka : kb + (size_t)j*NS) + pb8;
                            float4 a4 = *(const float4*)kp;
                            float4 b4 = *(const float4*)(kp + 4);
                            kv[j][0]=a4.x; kv[j][1]=a4.y; kv[j][2]=a4.z; kv[j][3]=a4.w;
                            kv[j][4]=b4.x; kv[j][5]=b4.y; kv[j][6]=b4.z; kv[j][7]=b4.w;
                        }
                        float4 a4 = *(const float4*)(src + pb8);
                        float4 b4 = *(const float4*)(src + pb8 + 4);
                        sv[0]=a4.x; sv[1]=a4.y; sv[2]=a4.z; sv[3]=a4.w;
                        sv[4]=b4.x; sv[5]=b4.y; sv[6]=b4.z; sv[7]=b4.w;
                    }
                    float s[8] = {0,0,0,0,0,0,0,0};
                    #pragma unroll
                    for (int j = 0; j < 5; j++) if (j < nc) {
                        float a = cf[j];
                        #pragma unroll
                        for (int c = 0; c < 8; c++) s[c] = fmaf(a, kv[j][c], s[c]);
                    }
                    #pragma unroll
                    for (int c = 0; c < 8; c++)
                        pz.h[c] = (_Float16)(sv[c] + dtc*s[c]);
                }
                return pz;
            };

            HU pz;
            if (q2 == 0) pz = zload(wid + 1);      // own rows 1..4 (issued pre-spin)
            if (gev > 1 && q2 == 1 && (wid == 0 || wid == 3)) {
                bool need = (wid == 0) ? (rg > 0) : (rg < 7);
                if (need) {
                    const int* fp = (wid == 0) ? &flagB[tile-1] : &flagT[tile+1];
                    while (__hip_atomic_load(fp, __ATOMIC_RELAXED,
                                             __HIP_MEMORY_SCOPE_SYSTEM) < gev-1)
                        __builtin_amdgcn_s_sleep(1);
                }
            }
            if (q2 == 1) pz = zload((wid == 0) ? 0 : ((wid == 3) ? 5 : -1));

            // ---- conv1 via MFMA from registers; act write (pi-permuted) ----
            auto wr_act = [&](int lr, const f32x16& a1, int oct, bool valid) {
                unsigned words[8];
                #pragma unroll
                for (int pr = 0; pr < 8; pr++) {
                    int r0 = 2*pr;
                    int oc0 = oct*32 + (r0 & 3) + 8*(r0 >> 2) + 4*q2;
                    float v0 = valid ? fmaxf(a1[r0]   + ts*s_w10v[oc0]
                                             + s_b1v[oc0],   0.0f) : 0.0f;
                    float v1 = valid ? fmaxf(a1[r0+1] + ts*s_w10v[oc0+1]
                                             + s_b1v[oc0+1], 0.0f) : 0.0f;
                    union { _Float16 h[2]; unsigned u; } pk;
                    pk.h[0] = (_Float16)v0; pk.h[1] = (_Float16)v1;
                    words[pr] = pk.u;
                }
                unsigned char* basep = s_pool + (size_t)(lr*32 + m32)*ACT_STRIDE
                                       + oct*64 + q2*32;
                *(uint4*)basep        = make_uint4(words[0],words[1],words[2],words[3]);
                *(uint4*)(basep + 16) = make_uint4(words[4],words[5],words[6],words[7]);
            };
            {
                f32x16 zz = (f32x16)(0.0f);
                f32x16 c0 = __builtin_amdgcn_mfma_f32_32x32x16_f16(w1lo[0], pz.h, zz, 0,0,0);
                f32x16 c1 = __builtin_amdgcn_mfma_f32_32x32x16_f16(w1lo[1], pz.h, zz, 0,0,0);
                wr_act(wid + 1, c0, 0, true);
                wr_act(wid + 1, c1, 1, true);
                if (wid == 0 || wid == 3) {
                    int lrh = (wid == 0) ? 0 : 5;
                    bool vh = (unsigned)(rg*4 - 1 + lrh) < 32u;
                    f32x16 d0 = __builtin_amdgcn_mfma_f32_32x32x16_f16(w1hi[0], pz.h, zz, 0,0,0);
                    f32x16 d1 = __builtin_amdgcn_mfma_f32_32x32x16_f16(w1hi[1], pz.h, zz, 0,0,0);
                    wr_act(lrh, d0, 0, vh);
                    wr_act(lrh, d1, 1, vh);
                }
            }
            __syncthreads();   // BARRIER-A: act complete

            // ---- conv2: center b128 loads + DPP kw shifts ----
            f32x16 acc2[2];
            acc2[0] = (f32x16)(0.0f);
            acc2[1] = (f32x16)(0.0f);
            {
                const unsigned char* actb = (const unsigned char*)s_pool;
                #pragma unroll 1
                for (int ks = 0; ks < 4; ks++) {
                    HU fc[4], d0[4], d2[4];
                    #pragma unroll
                    for (int l = 0; l < 4; l++) {
                        const unsigned char* p = actb
                            + (size_t)((rp*2 + l)*32 + m32)*ACT_STRIDE
                            + ks*32 + q2*16;
                        fc[l].v = *(const uint4*)p;
                    }
                    #pragma unroll
                    for (int l = 0; l < 4; l++) {
                        #pragma unroll
                        for (int i = 0; i < 4; i++) {
                            unsigned s0 = (unsigned)__builtin_amdgcn_update_dpp(
                                0, (int)fc[l].u[i], 0x138, 0xF, 0xF, true); // wave_shr:1
                            d0[l].u[i] = lz32 ? 0u : s0;
                            unsigned s2 = (unsigned)__builtin_amdgcn_update_dpp(
                                0, (int)fc[l].u[i], 0x130, 0xF, 0xF, true); // wave_shl:1
                            d2[l].u[i] = lz31 ? 0u : s2;
                        }
                    }
                    #pragma unroll
                    for (int kh = 0; kh < 3; kh++) {
                        #pragma unroll
                        for (int kw = 0; kw < 3; kw++) {
                            int tap = kh*3 + kw;
                            hfrag8 aw = *(const hfrag8*)
                                (w2p + (size_t)((tap*4 + ks)*2 + np)*512 + lane*8);
                            #pragma unroll
                            for (int ri = 0; ri < 2; ri++) {
                                int l = ri + kh;
                                hfrag8 bf = (kw == 0) ? d0[l].h
                                          : ((kw == 1) ? fc[l].h : d2[l].h);
                                acc2[ri] = __builtin_amdgcn_mfma_f32_32x32x16_f16(
                                    aw, bf, acc2[ri], 0, 0, 0);
                            }
                        }
                    }
                }
            }

            // ---- conv2 epilogue -> h2 (pi-permuted px-major fp16) ----
            {
                int ccase = (m32 == 0) ? 1 : ((m32 == 31) ? 2 : 0);
                #pragma unroll
                for (int ri = 0; ri < 2; ri++) {
                    int pg = rp*2 + ri;
                    int r_out = rg*4 + pg;
                    int rcase = (r_out == 0) ? 1 : ((r_out == 31) ? 2 : 0);
                    const float* tsb = &s_tsum[(rcase*3 + ccase)*64];
                    int px = pg*32 + m32;
                    unsigned words[8];
                    #pragma unroll
                    for (int pr = 0; pr < 8; pr++) {
                        int r0 = 2*pr;
                        int oc0 = np*32 + (r0 & 3) + 8*(r0 >> 2) + 4*q2;
                        float v0 = fmaxf(acc2[ri][r0]   + ts*tsb[oc0]
                                         + s_b2v[oc0],   0.0f);
                        float v1 = fmaxf(acc2[ri][r0+1] + ts*tsb[oc0+1]
                                         + s_b2v[oc0+1], 0.0f);
                        union { _Float16 h[2]; unsigned u; } pk;
                        pk.h[0] = (_Float16)v0; pk.h[1] = (_Float16)v1;
                        words[pr] = pk.u;
                    }
                    unsigned char* basep = s_h2 + (size_t)px*H2_STRIDE
                                           + np*64 + q2*32;
                    *(uint4*)basep        = make_uint4(words[0],words[1],words[2],words[3]);
                    *(uint4*)(basep + 16) = make_uint4(words[4],words[5],words[6],words[7]);
                }
            }
            __syncthreads();   // BARRIER-B: h2 complete

            // ---- conv3 via MFMA + mode epilogues ----
            float ls = 0.0f;
            {
                f32x16 a3a = (f32x16)(0.0f);
                #pragma unroll
                for (int kst = 0; kst < 4; kst++) {
                    HU f;
                    const unsigned char* p = s_h2
                        + (size_t)(wid*32 + m32)*H2_STRIDE + kst*32 + q2*16;
                    f.v = *(const uint4*)p;
                    a3a = __builtin_amdgcn_mfma_f32_32x32x16_f16(
                        w3f[kst], f.h, a3a, 0, 0, 0);
                }
                float a3[8];
                #pragma unroll
                for (int r = 0; r < 4; r++) {
                    float own = a3a[r];
                    float oth = __shfl(own, lane ^ 32, 64);
                    a3[r]     = q2 ? oth : own;
                    a3[4 + r] = q2 ? own : oth;
                }
                if (q2 == 0) {
                    #pragma unroll
                    for (int c = 0; c < 8; c++)
                        a3[c] += fmaf(ts, s_w30v[c], s_b3v[c]);
                    bool sysrow = (wid == 0) | (wid == 3);
                    int px = rg*128 + wid*32 + m32;
                    size_t pb8 = ((size_t)(b << 10) + px) << 3;
                    st8(kout + pb8, a3, sysrow);
                    if (mode == 1) {
                        float kv1[8], kv3[8], kv4[8], kv5[8], yv[8], r8[8];
                        ld8(ka + pb8, kv1, sysrow);
                        ld8(kb + 2*(size_t)NS + pb8, kv3, sysrow);
                        ld8(kb + 3*(size_t)NS + pb8, kv4, sysrow);
                        ld8(kb + 4*(size_t)NS + pb8, kv5, sysrow);
                        ld8(ya + pb8, yv, sysrow);
                        #pragma unroll
                        for (int c = 0; c < 8; c++)
                            r8[c] = yv[c] + dtc*(B1c*kv1[c] + B3c*kv3[c]
                                    + B4c*kv4[c] + B5c*kv5[c] + B6c*a3[c]);
                        st8(yb + pb8, r8, sysrow);
                    } else if (mode == 2) {
                        float kv1[8], kv3[8], kv4[8], kv5[8], kv6[8], yv[8], y5v[8];
                        ld8(ka + pb8, kv1, sysrow);
                        ld8(kb + 2*(size_t)NS + pb8, kv3, sysrow);
                        ld8(kb + 3*(size_t)NS + pb8, kv4, sysrow);
                        ld8(kb + 4*(size_t)NS + pb8, kv5, sysrow);
                        ld8(kb + 5*(size_t)NS + pb8, kv6, sysrow);
                        ld8(ya + pb8, yv, sysrow);
                        ld8(yb + pb8, y5v, sysrow);
                        #pragma unroll
                        for (int c = 0; c < 8; c++) {
                            float e = dtc*(E1c*kv1[c] + E3c*kv3[c] + E4c*kv4[c]
                                           + E5c*kv5[c] + E6c*kv6[c] + E7c*a3[c]);
                            float tol = ATOL + RTOL*fmaxf(fabsf(yv[c]), fabsf(y5v[c]));
                            float rr = e / tol;
                            ls += rr*rr;
                        }
                    }
                }
            }
            // per-wave drain then early halo release (no block barrier)
            asm volatile("s_waitcnt vmcnt(0)" ::: "memory");
            if (lane == 0 && wid == 0)
                __hip_atomic_store(&flagT[tile], gev, __ATOMIC_RELAXED,
                                   __HIP_MEMORY_SCOPE_SYSTEM);
            if (lane == 0 && wid == 3)
                __hip_atomic_store(&flagB[tile], gev, __ATOMIC_RELAXED,
                                   __HIP_MEMORY_SCOPE_SYSTEM);
            if (mode == 2) {
                s_red[tid] = ls;
                __syncthreads();
                for (int sft = 128; sft > 0; sft >>= 1) {
                    if (tid < sft) s_red[tid] += s_red[tid + sft];
                    __syncthreads();
                }
                if (tid == 0) st_sysf(&partp[tile], s_red[0]);
                __syncthreads();   // drains tid0's partp store
                if (tid == 0)
                    __hip_atomic_store(&flags[tile], gev, __ATOMIC_RELAXED,
                                       __HIP_MEMORY_SCOPE_SYSTEM);
            }
        }
    };

    int gev = 1;
    eval(ya, 0, g_cf[5], 0.0f, ka, 0, gev, part);   // k1 = f(t0, y0)
    gev++;

    for (int st = 0; st < 24; st++) {
        if (t >= 1.0f - 1e-7f) break;
        float* partp = part + (size_t)(st & 1)*512;
        for (int e = 0; e < 6; e++) {
            int nc = (e < 5) ? e + 1 : 0;
            const float* src = (e == 5) ? yb : ya;
            float* kout = (e < 5) ? kb + (size_t)(e + 1)*NS : kg;
            int mode = (e == 4) ? 1 : ((e == 5) ? 2 : 0);
            eval(src, nc, g_cf[e], g_ct[e], kout, mode, gev, partp);
            gev++;
        }
        wait_all(gev - 1);   // all tiles finished the err eval (partials at L3)
        float v = ld_sysf(&partp[tid]) + ld_sysf(&partp[tid + 256]);
        s_red[tid] = v;
        __syncthreads();
        for (int sft = 128; sft > 0; sft >>= 1) {
            if (tid < sft) s_red[tid] += s_red[tid + sft];
            __syncthreads();
        }
        float red0 = s_red[0];
        __syncthreads();
        float err_norm = sqrtf(red0 / (float)NS);
        float dtc = fminf(dt, 1.0f - t);
        bool adv = (err_norm <= 1.0f);
        if (adv) {
            t = t + dtc;
            float* tmp = ya; ya = yb; yb = tmp;   // y <- y5
            tmp = ka; ka = kg; kg = tmp;          // k1 <- k7 (FSAL)
        }
        float safe = fmaxf(err_norm, 1e-10f);
        float factor = fminf(fmaxf(0.9f*powf(safe, -0.2f), 0.2f), 10.0f);
        dt = dtc*factor;
    }

    // flush private interior rows of final y to L3, then publish + wait
    for (int tile = blockIdx.x; tile < 512; tile += nblk) {
        int b = tile >> 3, rg = tile & 7;
        if (tid < 128) {
            int lrow = tid >> 5;
            if (lrow == 1 || lrow == 2) {
                int px = rg*128 + tid;
                float* yp = ya + (((size_t)(b << 10) + px) << 3);
                float4 v0 = *(const float4*)yp;
                float4 v1 = *(const float4*)(yp + 4);
                st_sysf2(yp,     v0.x, v0.y);
                st_sysf2(yp + 2, v0.z, v0.w);
                st_sysf2(yp + 4, v1.x, v1.y);
                st_sysf2(yp + 6, v1.z, v1.w);
            }
        }
    }
    __syncthreads();
    for (int tile = blockIdx.x; tile < 512; tile += nblk)
        if (tid == 0)
            __hip_atomic_store(&flags[tile], gev, __ATOMIC_RELAXED,
                               __HIP_MEMORY_SCOPE_SYSTEM);
    wait_all(gev);

    // final linear head
    for (int bh = blockIdx.x; bh < 64; bh += nblk) {
        float* s_hred = (float*)s_pool;   // 10*256 floats overlay
        float acc[10];
        #pragma unroll
        for (int m = 0; m < 10; m++) acc[m] = 0.0f;
        for (int px = tid; px < 1024; px += 256) {
            const float* yp = ya + (((size_t)(bh << 10) + px) << 3);
            float yv[8];
            #pragma unroll
            for (int h = 0; h < 4; h++) {
                float2 v = ld_sysf2(yp + 2*h);
                yv[2*h] = v.x; yv[2*h+1] = v.y;
            }
            #pragma unroll
            for (int c = 0; c < 8; c++) {
                float v = yv[c];
                #pragma unroll
                for (int m = 0; m < 10; m++)
                    acc[m] = fmaf(v, wl[(size_t)m*8192 + (c << 10) + px], acc[m]);
            }
        }
        #pragma unroll
        for (int m = 0; m < 10; m++) s_hred[m*256 + tid] = acc[m];
        __syncthreads();
        for (int sft = 128; sft > 0; sft >>= 1) {
            if (tid < sft) {
                #pragma unroll
                for (int m = 0; m < 10; m++)
                    s_hred[m*256 + tid] += s_hred[m*256 + tid + sft];
            }
            __syncthreads();
        }
        if (tid < 10) out[bh*10 + tid] = s_hred[tid*256] + bl[tid];
        __syncthreads();
    }
}

// ---------------- host ----------------
extern "C" void kernel_launch(void* const* d_in, const int* in_sizes, int n_in,
                              void* d_out, int out_size, void* d_ws, size_t ws_size,
                              hipStream_t stream)
{
    const float* x  = (const float*)d_in[0];
    const float* w1 = (const float*)d_in[1];
    const float* b1 = (const float*)d_in[2];
    const float* w2 = (const float*)d_in[3];
    const float* b2 = (const float*)d_in[4];
    const float* w3 = (const float*)d_in[5];
    const float* b3 = (const float*)d_in[6];
    const float* wl = (const float*)d_in[7];
    const float* bl = (const float*)d_in[8];
    float* out = (float*)d_out;

    float* F = (float*)d_ws;
    float* part = F + OFF_PART;
    int*   flags = (int*)(F + OFF_FLAG);
    float* tsum = F + OFF_TSUM;
    _Float16* w2p = (_Float16*)(F + OFF_W2P);
    float* y    = F + OFF_Y;
    float* y5   = F + OFF_Y5;
    float* kbp  = F + OFF_K;
    float* wpk  = F + OFF_WPK;
    int*   flagT = (int*)(F + OFF_FT);
    int*   flagB = (int*)(F + OFF_FB);

    k_init<<<NS/256, 256, 0, stream>>>(x, y, flags, flagT, flagB);
    k_prepack<<<144, 256, 0, stream>>>(w1, w2, w3, w2p, tsum, wpk);

    int maxb = 0;
    if (hipOccupancyMaxActiveBlocksPerMultiprocessor(&maxb,
            reinterpret_cast<const void*>(k_ode), 256, 0) != hipSuccess || maxb < 1)
        maxb = 1;
    int cus = 256;
    {
        int dev = 0;
        hipGetDevice(&dev);
        hipDeviceProp_t prop;
        if (hipGetDeviceProperties(&prop, dev) == hipSuccess && prop.multiProcessorCount > 0)
            cus = prop.multiProcessorCount;
    }
    long cap = (long)maxb * (long)cus;
    int gridn = (int)((cap < 512) ? cap : 512);
    if (gridn < 16) gridn = 16;

    k_ode<<<gridn, 256, 0, stream>>>(b1, b2, b3, w2p, tsum, wpk, wl, bl,
                                     y, y5, kbp, part, flags, flagT, flagB, out);
}

// Round 6
// 399.340 us; speedup vs baseline: 1.5675x; 1.0211x over previous
//
#include <hip/hip_runtime.h>
#include <math.h>

namespace {
constexpr int BN = 64;
constexpr int HW = 1024;
constexpr int NS = BN*8*HW;      // 524288

constexpr float C2f = 0.2f, C3f = 0.3f, C4f = 0.8f, C5f = (float)(8.0/9.0);
constexpr float A21 = 0.2f;
constexpr float A31 = (float)(3.0/40.0),  A32 = (float)(9.0/40.0);
constexpr float A41 = (float)(44.0/45.0), A42 = (float)(-56.0/15.0), A43 = (float)(32.0/9.0);
constexpr float A51 = (float)(19372.0/6561.0), A52 = (float)(-25360.0/2187.0),
                A53 = (float)(64448.0/6561.0), A54 = (float)(-212.0/729.0);
constexpr float A61 = (float)(9017.0/3168.0), A62 = (float)(-355.0/33.0),
                A63 = (float)(46732.0/5247.0), A64 = (float)(49.0/176.0),
                A65 = (float)(-5103.0/18656.0);
constexpr float B1c = (float)(35.0/384.0), B3c = (float)(500.0/1113.0),
                B4c = (float)(125.0/192.0), B5c = (float)(-2187.0/6784.0),
                B6c = (float)(11.0/84.0);
constexpr float E1c = (float)(71.0/57600.0), E3c = (float)(-71.0/16695.0),
                E4c = (float)(71.0/1920.0), E5c = (float)(-17253.0/339200.0),
                E6c = (float)(22.0/525.0),  E7c = (float)(-1.0/40.0);
constexpr float RTOL = 1e-3f, ATOL = 1e-3f;

// ws layout (floats / ints)
constexpr size_t OFF_PART = 0;        // 1024 floats (double-buffered by step parity)
constexpr size_t OFF_FLAG = 1024;     // 512 ints (tile fully done; step gate)
constexpr size_t OFF_CNT  = 1536;     // unused, kept
constexpr size_t OFF_TSUM = 1600;     // 576
constexpr size_t OFF_W2P  = 2176;     // 36864 halfs = 18432 floats
constexpr size_t OFF_Y    = 20608;    // y buffers px-major: [b][px][8]
constexpr size_t OFF_Y5   = OFF_Y  + (size_t)NS;
constexpr size_t OFF_K    = OFF_Y5 + (size_t)NS;   // 7*NS (k1..k7, px-major)
constexpr size_t OFF_WPK  = OFF_K + (size_t)7*NS;  // w1t(512) w10(64) w3t(512) w30(8)
constexpr size_t OFF_FT   = OFF_WPK + 1152;        // 512 ints: top-row ready
constexpr size_t OFF_FB   = OFF_FT + 512;          // 512 ints: bottom-row ready

// LDS strides (bytes), both == 4 dwords (mod 32): b128 ops tile banks (R0-style).
constexpr int ACT_STRIDE = 272;   // 192 px rows (6x32), 128B payload
constexpr int H2_STRIDE  = 144;   // 128 px rows, 128B payload
}

__constant__ float g_cf[6][5] = {
    {A21, 0, 0, 0, 0},
    {A31, A32, 0, 0, 0},
    {A41, A42, A43, 0, 0},
    {A51, A52, A53, A54, 0},
    {A61, A62, A63, A64, A65},
    {0, 0, 0, 0, 0}};
__constant__ float g_ct[6] = {C2f, C3f, C4f, C5f, 1.0f, 1.0f};

typedef _Float16 hfrag8 __attribute__((ext_vector_type(8)));
typedef float f32x16 __attribute__((ext_vector_type(16)));

union HU { hfrag8 h; unsigned u[4]; uint4 v; };

// ---- system-scope (L3-coherent) accessors ----
__device__ __forceinline__ float ld_sysf(const float* p) {
    return __hip_atomic_load(p, __ATOMIC_RELAXED, __HIP_MEMORY_SCOPE_SYSTEM);
}
__device__ __forceinline__ float2 ld_sysf2(const float* p) {
    union { unsigned long long u; float2 f; } c;
    c.u = __hip_atomic_load((const unsigned long long*)p, __ATOMIC_RELAXED,
                            __HIP_MEMORY_SCOPE_SYSTEM);
    return c.f;
}
__device__ __forceinline__ void st_sysf(float* p, float v) {
    __hip_atomic_store(p, v, __ATOMIC_RELAXED, __HIP_MEMORY_SCOPE_SYSTEM);
}
__device__ __forceinline__ void st_sysf2(float* p, float a, float b) {
    union { unsigned long long u; float2 f; } c;
    c.f = make_float2(a, b);
    __hip_atomic_store((unsigned long long*)p, c.u, __ATOMIC_RELAXED,
                       __HIP_MEMORY_SCOPE_SYSTEM);
}

// 8-float load/store; sys = NEIGHBOR-written (L3) vs self-written (L2 plain)
__device__ __forceinline__ void ld8(const float* p, float* v, bool sys) {
    if (sys) {
        #pragma unroll
        for (int h = 0; h < 4; h++) {
            float2 t = ld_sysf2(p + 2*h);
            v[2*h] = t.x; v[2*h+1] = t.y;
        }
    } else {
        float4 a = *(const float4*)p;
        float4 b = *(const float4*)(p + 4);
        v[0]=a.x; v[1]=a.y; v[2]=a.z; v[3]=a.w;
        v[4]=b.x; v[5]=b.y; v[6]=b.z; v[7]=b.w;
    }
}
__device__ __forceinline__ void st8(float* p, const float* v, bool sys) {
    if (sys) {
        st_sysf2(p,     v[0], v[1]);
        st_sysf2(p + 2, v[2], v[3]);
        st_sysf2(p + 4, v[4], v[5]);
        st_sysf2(p + 6, v[6], v[7]);
    } else {
        *(float4*)p       = make_float4(v[0], v[1], v[2], v[3]);
        *(float4*)(p + 4) = make_float4(v[4], v[5], v[6], v[7]);
    }
}

// ---------------- init ----------------
__global__ __launch_bounds__(256)
void k_init(const float* __restrict__ x, float* __restrict__ y,
            int* __restrict__ flags, int* __restrict__ flagT,
            int* __restrict__ flagB)
{
    int idx = blockIdx.x*256 + threadIdx.x;           // < NS
    int b = idx >> 13, px = (idx >> 3) & 1023, c = idx & 7;
    y[idx] = (c < 3) ? x[(size_t)(b*3 + c)*1024 + px] : 0.0f;
    if (idx < 512) { flags[idx] = 0; flagT[idx] = 0; flagB[idx] = 0; }
}

// ---------------- prepack ----------------
// channel permutation pi(ch) = oct*32 + q2*16 + r  (MFMA C-reg order) so conv
// epilogues write 32B-contiguous chunks. w2p/w3 consume with inverse perm.
__global__ __launch_bounds__(256)
void k_prepack(const float* __restrict__ w1, const float* __restrict__ w2,
               const float* __restrict__ w3, _Float16* __restrict__ w2p,
               float* __restrict__ tsum, float* __restrict__ wpk)
{
    int gid = blockIdx.x*256 + threadIdx.x;
    if (gid < 36864) {
        int j    = gid & 7;
        int lane = (gid >> 3) & 63;
        int nt   = (gid >> 9) & 1;
        int ks   = (gid >> 10) & 3;
        int tap  = gid >> 12;            // 0..8
        int oc = nt*32 + (lane & 31);
        int kpos = ks*16 + (lane >> 5)*8 + j;
        int oct = kpos >> 5, q2b = (kpos >> 4) & 1, rr = kpos & 15;
        int ic = oct*32 + (rr & 3) + (q2b << 2) + ((rr >> 2) << 3);  // inv-pi
        w2p[gid] = (_Float16)w2[oc*585 + (1 + ic)*9 + tap];
    }
    if (gid < 576) {
        int oc = gid & 63, combo = gid >> 6;       // 0..8
        int rcase = combo / 3, ccase = combo % 3;
        float s = 0.0f;
        for (int kh = 0; kh < 3; kh++) {
            if ((rcase == 1 && kh == 0) || (rcase == 2 && kh == 2)) continue;
            for (int kw = 0; kw < 3; kw++) {
                if ((ccase == 1 && kw == 0) || (ccase == 2 && kw == 2)) continue;
                s += w2[oc*585 + kh*3 + kw];
            }
        }
        tsum[gid] = s;
    }
    // w1t: wpk[c*64 + o] = w1[o*9 + 1 + c]
    if (gid < 512) wpk[gid] = w1[(gid & 63)*9 + 1 + (gid >> 6)];
    // w10[o]
    if (gid < 64)  wpk[512 + gid] = w1[gid*9];
    // w3t: wpk[576 + c*8 + o] = w3[o*65 + 1 + c]
    if (gid < 512) wpk[576 + gid] = w3[(gid & 7)*65 + 1 + (gid >> 3)];
    // w30[o]
    if (gid < 8)   wpk[1088 + gid] = w3[gid*65];
}

// ---------------- the whole ODE solve ----------------
// R5 (resubmit): sys-scope only for NEIGHBOR-written rows (zload lr 0/5);
// self-written data (own rows 1-4, mode-epilogue operands) via plain L2-hit
// loads (write-through L1 store-invalidate => same-wave coherent).
// Reductions via wave shfl_xor (1 barrier instead of 8).
__global__ void __launch_bounds__(256, 2)
k_ode(const float* __restrict__ b1, const float* __restrict__ b2,
      const float* __restrict__ b3, const _Float16* __restrict__ w2p,
      const float* __restrict__ tsumg, const float* __restrict__ wpk,
      const float* __restrict__ wl, const float* __restrict__ bl,
      float* __restrict__ ybuf, float* __restrict__ y5buf,
      float* __restrict__ kb, float* __restrict__ part,
      int* __restrict__ flags, int* __restrict__ flagT,
      int* __restrict__ flagB, float* __restrict__ out)
{
    __shared__ __align__(16) unsigned char s_pool[192*ACT_STRIDE]; // 52224
    __shared__ __align__(16) unsigned char s_h2[128*H2_STRIDE];    // 18432
    __shared__ float s_tsum[576];
    __shared__ float s_b2v[64], s_b1v[64], s_w10v[64];
    __shared__ float s_w30v[8], s_b3v[8];
    __shared__ float s_red[8];

    const int tid = threadIdx.x;
    const int nblk = gridDim.x;
    const int lane = tid & 63;
    const int m32 = lane & 31, q2 = lane >> 5;
    const int rp = tid >> 7;          // row-pair for conv2
    const int np = (tid >> 6) & 1;    // oc-half for conv2
    const int wid = tid >> 6;         // wave id
    const bool lz32 = (lane == 32);
    const bool lz31 = (lane == 31);

    if (tid < 64) {
        s_b2v[tid] = b2[tid];
        s_b1v[tid] = b1[tid];
        s_w10v[tid] = wpk[512 + tid];
    }
    if (tid < 8) { s_w30v[tid] = wpk[1088 + tid]; s_b3v[tid] = b3[tid]; }
    for (int i = tid; i < 576; i += 256) s_tsum[i] = tsumg[i];
    __syncthreads();

    // resident conv1 A-frags: lo (k=0..7 live) and hi (k=8..15 live)
    hfrag8 w1lo[2], w1hi[2];
    #pragma unroll
    for (int oct = 0; oct < 2; oct++)
        #pragma unroll
        for (int j = 0; j < 8; j++) {
            _Float16 wv = (_Float16)wpk[j*64 + oct*32 + m32];
            w1lo[oct][j] = q2 ? (_Float16)0.0f : wv;
            w1hi[oct][j] = q2 ? wv : (_Float16)0.0f;
        }
    // resident conv3 A-frags (channel positions permuted by inv-pi)
    hfrag8 w3f[4];
    #pragma unroll
    for (int kst = 0; kst < 4; kst++)
        #pragma unroll
        for (int j = 0; j < 8; j++) {
            int kpos = kst*16 + q2*8 + j;
            int oct = kpos >> 5, q2b = (kpos >> 4) & 1, rr = kpos & 15;
            int ch = oct*32 + (rr & 3) + (q2b << 2) + ((rr >> 2) << 3);
            w3f[kst][j] = (m32 < 8) ? (_Float16)wpk[576 + ch*8 + m32]
                                    : (_Float16)0.0f;
        }

    float t = 0.0f, dt = 0.1f;
    float* ya = ybuf; float* yb = y5buf;
    float* ka = kb;  float* kg = kb + 6*(size_t)NS;

    auto wait_all = [&](int target) {
        for (;;) {
            bool ok = (__hip_atomic_load(&flags[tid], __ATOMIC_RELAXED,
                           __HIP_MEMORY_SCOPE_SYSTEM) >= target)
                   && (__hip_atomic_load(&flags[tid + 256], __ATOMIC_RELAXED,
                           __HIP_MEMORY_SCOPE_SYSTEM) >= target);
            if (__syncthreads_and((int)ok)) break;
            __builtin_amdgcn_s_sleep(2);
        }
    };

    auto eval = [&](const float* src, int nc, const float* cf, float ctv,
                    float* kout, int mode, int gev, float* partp) {
        float dtc = fminf(dt, 1.0f - t);
        float ts  = t + ctv*dtc;

        for (int tile = blockIdx.x; tile < 512; tile += nblk) {
            int b = tile >> 3, rg = tile & 7;

            // ---- z-combine into registers (per-lane row) ----
            auto zload = [&](int lr) {
                HU pz; pz.v = make_uint4(0u,0u,0u,0u);
                int r = rg*4 - 1 + lr;
                if ((unsigned)lr < 6u && (unsigned)r < 32u) {
                    bool nbr = (lr == 0) | (lr == 5);   // neighbor-written only
                    int px = (r << 5) + m32;
                    size_t pb8 = ((size_t)(b << 10) + px) << 3;
                    float kv[5][8], sv[8];
                    if (nbr) {
                        #pragma unroll
                        for (int j = 0; j < 5; j++) if (j < nc) {
                            const float* kp = (j == 0 ? ka : kb + (size_t)j*NS) + pb8;
                            #pragma unroll
                            for (int h = 0; h < 4; h++) {
                                float2 t2 = ld_sysf2(kp + 2*h);
                                kv[j][2*h] = t2.x; kv[j][2*h+1] = t2.y;
                            }
                        }
                        #pragma unroll
                        for (int h = 0; h < 4; h++) {
                            float2 t2 = ld_sysf2(src + pb8 + 2*h);
                            sv[2*h] = t2.x; sv[2*h+1] = t2.y;
                        }
                    } else {
                        #pragma unroll
                        for (int j = 0; j < 5; j++) if (j < nc) {
                            const float* kp = (j == 0 ? ka : kb + (size_t)j*NS) + pb8;
                            float4 a4 = *(const float4*)kp;
                            float4 b4 = *(const float4*)(kp + 4);
                            kv[j][0]=a4.x; kv[j][1]=a4.y; kv[j][2]=a4.z; kv[j][3]=a4.w;
                            kv[j][4]=b4.x; kv[j][5]=b4.y; kv[j][6]=b4.z; kv[j][7]=b4.w;
                        }
                        float4 a4 = *(const float4*)(src + pb8);
                        float4 b4 = *(const float4*)(src + pb8 + 4);
                        sv[0]=a4.x; sv[1]=a4.y; sv[2]=a4.z; sv[3]=a4.w;
                        sv[4]=b4.x; sv[5]=b4.y; sv[6]=b4.z; sv[7]=b4.w;
                    }
                    float s[8] = {0,0,0,0,0,0,0,0};
                    #pragma unroll
                    for (int j = 0; j < 5; j++) if (j < nc) {
                        float a = cf[j];
                        #pragma unroll
                        for (int c = 0; c < 8; c++) s[c] = fmaf(a, kv[j][c], s[c]);
                    }
                    #pragma unroll
                    for (int c = 0; c < 8; c++)
                        pz.h[c] = (_Float16)(sv[c] + dtc*s[c]);
                }
                return pz;
            };

            HU pz;
            if (q2 == 0) pz = zload(wid + 1);      // own rows 1..4 (issued pre-spin)
            if (gev > 1 && q2 == 1 && (wid == 0 || wid == 3)) {
                bool need = (wid == 0) ? (rg > 0) : (rg < 7);
                if (need) {
                    const int* fp = (wid == 0) ? &flagB[tile-1] : &flagT[tile+1];
                    while (__hip_atomic_load(fp, __ATOMIC_RELAXED,
                                             __HIP_MEMORY_SCOPE_SYSTEM) < gev-1)
                        __builtin_amdgcn_s_sleep(1);
                }
            }
            if (q2 == 1) pz = zload((wid == 0) ? 0 : ((wid == 3) ? 5 : -1));

            // ---- conv1 via MFMA from registers; act write (pi-permuted) ----
            auto wr_act = [&](int lr, const f32x16& a1, int oct, bool valid) {
                unsigned words[8];
                #pragma unroll
                for (int pr = 0; pr < 8; pr++) {
                    int r0 = 2*pr;
                    int oc0 = oct*32 + (r0 & 3) + 8*(r0 >> 2) + 4*q2;
                    float v0 = valid ? fmaxf(a1[r0]   + ts*s_w10v[oc0]
                                             + s_b1v[oc0],   0.0f) : 0.0f;
                    float v1 = valid ? fmaxf(a1[r0+1] + ts*s_w10v[oc0+1]
                                             + s_b1v[oc0+1], 0.0f) : 0.0f;
                    union { _Float16 h[2]; unsigned u; } pk;
                    pk.h[0] = (_Float16)v0; pk.h[1] = (_Float16)v1;
                    words[pr] = pk.u;
                }
                unsigned char* basep = s_pool + (size_t)(lr*32 + m32)*ACT_STRIDE
                                       + oct*64 + q2*32;
                *(uint4*)basep        = make_uint4(words[0],words[1],words[2],words[3]);
                *(uint4*)(basep + 16) = make_uint4(words[4],words[5],words[6],words[7]);
            };
            {
                f32x16 zz = (f32x16)(0.0f);
                f32x16 c0 = __builtin_amdgcn_mfma_f32_32x32x16_f16(w1lo[0], pz.h, zz, 0,0,0);
                f32x16 c1 = __builtin_amdgcn_mfma_f32_32x32x16_f16(w1lo[1], pz.h, zz, 0,0,0);
                wr_act(wid + 1, c0, 0, true);
                wr_act(wid + 1, c1, 1, true);
                if (wid == 0 || wid == 3) {
                    int lrh = (wid == 0) ? 0 : 5;
                    bool vh = (unsigned)(rg*4 - 1 + lrh) < 32u;
                    f32x16 d0 = __builtin_amdgcn_mfma_f32_32x32x16_f16(w1hi[0], pz.h, zz, 0,0,0);
                    f32x16 d1 = __builtin_amdgcn_mfma_f32_32x32x16_f16(w1hi[1], pz.h, zz, 0,0,0);
                    wr_act(lrh, d0, 0, vh);
                    wr_act(lrh, d1, 1, vh);
                }
            }
            __syncthreads();   // BARRIER-A: act complete

            // ---- conv2: center b128 loads + DPP kw shifts ----
            f32x16 acc2[2];
            acc2[0] = (f32x16)(0.0f);
            acc2[1] = (f32x16)(0.0f);
            {
                const unsigned char* actb = (const unsigned char*)s_pool;
                #pragma unroll 1
                for (int ks = 0; ks < 4; ks++) {
                    HU fc[4], d0[4], d2[4];
                    #pragma unroll
                    for (int l = 0; l < 4; l++) {
                        const unsigned char* p = actb
                            + (size_t)((rp*2 + l)*32 + m32)*ACT_STRIDE
                            + ks*32 + q2*16;
                        fc[l].v = *(const uint4*)p;
                    }
                    #pragma unroll
                    for (int l = 0; l < 4; l++) {
                        #pragma unroll
                        for (int i = 0; i < 4; i++) {
                            unsigned s0 = (unsigned)__builtin_amdgcn_update_dpp(
                                0, (int)fc[l].u[i], 0x138, 0xF, 0xF, true); // wave_shr:1
                            d0[l].u[i] = lz32 ? 0u : s0;
                            unsigned s2 = (unsigned)__builtin_amdgcn_update_dpp(
                                0, (int)fc[l].u[i], 0x130, 0xF, 0xF, true); // wave_shl:1
                            d2[l].u[i] = lz31 ? 0u : s2;
                        }
                    }
                    #pragma unroll
                    for (int kh = 0; kh < 3; kh++) {
                        #pragma unroll
                        for (int kw = 0; kw < 3; kw++) {
                            int tap = kh*3 + kw;
                            hfrag8 aw = *(const hfrag8*)
                                (w2p + (size_t)((tap*4 + ks)*2 + np)*512 + lane*8);
                            #pragma unroll
                            for (int ri = 0; ri < 2; ri++) {
                                int l = ri + kh;
                                hfrag8 bf = (kw == 0) ? d0[l].h
                                          : ((kw == 1) ? fc[l].h : d2[l].h);
                                acc2[ri] = __builtin_amdgcn_mfma_f32_32x32x16_f16(
                                    aw, bf, acc2[ri], 0, 0, 0);
                            }
                        }
                    }
                }
            }

            // ---- conv2 epilogue -> h2 (pi-permuted px-major fp16) ----
            {
                int ccase = (m32 == 0) ? 1 : ((m32 == 31) ? 2 : 0);
                #pragma unroll
                for (int ri = 0; ri < 2; ri++) {
                    int pg = rp*2 + ri;
                    int r_out = rg*4 + pg;
                    int rcase = (r_out == 0) ? 1 : ((r_out == 31) ? 2 : 0);
                    const float* tsb = &s_tsum[(rcase*3 + ccase)*64];
                    int px = pg*32 + m32;
                    unsigned words[8];
                    #pragma unroll
                    for (int pr = 0; pr < 8; pr++) {
                        int r0 = 2*pr;
                        int oc0 = np*32 + (r0 & 3) + 8*(r0 >> 2) + 4*q2;
                        float v0 = fmaxf(acc2[ri][r0]   + ts*tsb[oc0]
                                         + s_b2v[oc0],   0.0f);
                        float v1 = fmaxf(acc2[ri][r0+1] + ts*tsb[oc0+1]
                                         + s_b2v[oc0+1], 0.0f);
                        union { _Float16 h[2]; unsigned u; } pk;
                        pk.h[0] = (_Float16)v0; pk.h[1] = (_Float16)v1;
                        words[pr] = pk.u;
                    }
                    unsigned char* basep = s_h2 + (size_t)px*H2_STRIDE
                                           + np*64 + q2*32;
                    *(uint4*)basep        = make_uint4(words[0],words[1],words[2],words[3]);
                    *(uint4*)(basep + 16) = make_uint4(words[4],words[5],words[6],words[7]);
                }
            }
            __syncthreads();   // BARRIER-B: h2 complete

            // ---- conv3 via MFMA + mode epilogues ----
            float ls = 0.0f;
            {
                f32x16 a3a = (f32x16)(0.0f);
                #pragma unroll
                for (int kst = 0; kst < 4; kst++) {
                    HU f;
                    const unsigned char* p = s_h2
                        + (size_t)(wid*32 + m32)*H2_STRIDE + kst*32 + q2*16;
                    f.v = *(const uint4*)p;
                    a3a = __builtin_amdgcn_mfma_f32_32x32x16_f16(
                        w3f[kst], f.h, a3a, 0, 0, 0);
                }
                float a3[8];
                #pragma unroll
                for (int r = 0; r < 4; r++) {
                    float own = a3a[r];
                    float oth = __shfl(own, lane ^ 32, 64);
                    a3[r]     = q2 ? oth : own;
                    a3[4 + r] = q2 ? own : oth;
                }
                if (q2 == 0) {
                    #pragma unroll
                    for (int c = 0; c < 8; c++)
                        a3[c] += fmaf(ts, s_w30v[c], s_b3v[c]);
                    bool sysrow = (wid == 0) | (wid == 3);
                    int px = rg*128 + wid*32 + m32;
                    size_t pb8 = ((size_t)(b << 10) + px) << 3;
                    st8(kout + pb8, a3, sysrow);
                    if (mode == 1) {
                        float kv1[8], kv3[8], kv4[8], kv5[8], yv[8], r8[8];
                        ld8(ka + pb8, kv1, false);
                        ld8(kb + 2*(size_t)NS + pb8, kv3, false);
                        ld8(kb + 3*(size_t)NS + pb8, kv4, false);
                        ld8(kb + 4*(size_t)NS + pb8, kv5, false);
                        ld8(ya + pb8, yv, false);
                        #pragma unroll
                        for (int c = 0; c < 8; c++)
                            r8[c] = yv[c] + dtc*(B1c*kv1[c] + B3c*kv3[c]
                                    + B4c*kv4[c] + B5c*kv5[c] + B6c*a3[c]);
                        st8(yb + pb8, r8, sysrow);
                    } else if (mode == 2) {
                        float kv1[8], kv3[8], kv4[8], kv5[8], kv6[8], yv[8], y5v[8];
                        ld8(ka + pb8, kv1, false);
                        ld8(kb + 2*(size_t)NS + pb8, kv3, false);
                        ld8(kb + 3*(size_t)NS + pb8, kv4, false);
                        ld8(kb + 4*(size_t)NS + pb8, kv5, false);
                        ld8(kb + 5*(size_t)NS + pb8, kv6, false);
                        ld8(ya + pb8, yv, false);
                        ld8(yb + pb8, y5v, false);
                        #pragma unroll
                        for (int c = 0; c < 8; c++) {
                            float e = dtc*(E1c*kv1[c] + E3c*kv3[c] + E4c*kv4[c]
                                           + E5c*kv5[c] + E6c*kv6[c] + E7c*a3[c]);
                            float tol = ATOL + RTOL*fmaxf(fabsf(yv[c]), fabsf(y5v[c]));
                            float rr = e / tol;
                            ls += rr*rr;
                        }
                    }
                }
            }
            // per-wave drain then early halo release (no block barrier)
            asm volatile("s_waitcnt vmcnt(0)" ::: "memory");
            if (lane == 0 && wid == 0)
                __hip_atomic_store(&flagT[tile], gev, __ATOMIC_RELAXED,
                                   __HIP_MEMORY_SCOPE_SYSTEM);
            if (lane == 0 && wid == 3)
                __hip_atomic_store(&flagB[tile], gev, __ATOMIC_RELAXED,
                                   __HIP_MEMORY_SCOPE_SYSTEM);
            if (mode == 2) {
                float v = ls;
                #pragma unroll
                for (int off = 1; off < 64; off <<= 1)
                    v += __shfl_xor(v, off, 64);
                if (lane == 0) s_red[wid] = v;
                __syncthreads();
                if (tid == 0) {
                    st_sysf(&partp[tile],
                            s_red[0] + s_red[1] + s_red[2] + s_red[3]);
                    asm volatile("s_waitcnt vmcnt(0)" ::: "memory");
                    __hip_atomic_store(&flags[tile], gev, __ATOMIC_RELAXED,
                                       __HIP_MEMORY_SCOPE_SYSTEM);
                }
            }
        }
    };

    int gev = 1;
    eval(ya, 0, g_cf[5], 0.0f, ka, 0, gev, part);   // k1 = f(t0, y0)
    gev++;

    for (int st = 0; st < 24; st++) {
        if (t >= 1.0f - 1e-7f) break;
        float* partp = part + (size_t)(st & 1)*512;
        for (int e = 0; e < 6; e++) {
            int nc = (e < 5) ? e + 1 : 0;
            const float* src = (e == 5) ? yb : ya;
            float* kout = (e < 5) ? kb + (size_t)(e + 1)*NS : kg;
            int mode = (e == 4) ? 1 : ((e == 5) ? 2 : 0);
            eval(src, nc, g_cf[e], g_ct[e], kout, mode, gev, partp);
            gev++;
        }
        wait_all(gev - 1);   // all tiles finished the err eval (partials at L3)
        float v = ld_sysf(&partp[tid]) + ld_sysf(&partp[tid + 256]);
        #pragma unroll
        for (int off = 1; off < 64; off <<= 1)
            v += __shfl_xor(v, off, 64);
        if (lane == 0) s_red[wid] = v;
        __syncthreads();
        float red0 = s_red[0] + s_red[1] + s_red[2] + s_red[3];
        float err_norm = sqrtf(red0 / (float)NS);
        float dtc = fminf(dt, 1.0f - t);
        bool adv = (err_norm <= 1.0f);
        if (adv) {
            t = t + dtc;
            float* tmp = ya; ya = yb; yb = tmp;   // y <- y5
            tmp = ka; ka = kg; kg = tmp;          // k1 <- k7 (FSAL)
        }
        float safe = fmaxf(err_norm, 1e-10f);
        float factor = fminf(fmaxf(0.9f*powf(safe, -0.2f), 0.2f), 10.0f);
        dt = dtc*factor;
    }

    // flush private interior rows of final y to L3, then publish + wait
    for (int tile = blockIdx.x; tile < 512; tile += nblk) {
        int b = tile >> 3, rg = tile & 7;
        if (tid < 128) {
            int lrow = tid >> 5;
            if (lrow == 1 || lrow == 2) {
                int px = rg*128 + tid;
                float* yp = ya + (((size_t)(b << 10) + px) << 3);
                float4 v0 = *(const float4*)yp;
                float4 v1 = *(const float4*)(yp + 4);
                st_sysf2(yp,     v0.x, v0.y);
                st_sysf2(yp + 2, v0.z, v0.w);
                st_sysf2(yp + 4, v1.x, v1.y);
                st_sysf2(yp + 6, v1.z, v1.w);
            }
        }
    }
    __syncthreads();
    for (int tile = blockIdx.x; tile < 512; tile += nblk)
        if (tid == 0)
            __hip_atomic_store(&flags[tile], gev, __ATOMIC_RELAXED,
                               __HIP_MEMORY_SCOPE_SYSTEM);
    wait_all(gev);

    // final linear head
    for (int bh = blockIdx.x; bh < 64; bh += nblk) {
        float* s_hred = (float*)s_pool;   // 10*256 floats overlay
        float acc[10];
        #pragma unroll
        for (int m = 0; m < 10; m++) acc[m] = 0.0f;
        for (int px = tid; px < 1024; px += 256) {
            const float* yp = ya + (((size_t)(bh << 10) + px) << 3);
            float yv[8];
            #pragma unroll
            for (int h = 0; h < 4; h++) {
                float2 v = ld_sysf2(yp + 2*h);
                yv[2*h] = v.x; yv[2*h+1] = v.y;
            }
            #pragma unroll
            for (int c = 0; c < 8; c++) {
                float v = yv[c];
                #pragma unroll
                for (int m = 0; m < 10; m++)
                    acc[m] = fmaf(v, wl[(size_t)m*8192 + (c << 10) + px], acc[m]);
            }
        }
        #pragma unroll
        for (int m = 0; m < 10; m++) s_hred[m*256 + tid] = acc[m];
        __syncthreads();
        for (int sft = 128; sft > 0; sft >>= 1) {
            if (tid < sft) {
                #pragma unroll
                for (int m = 0; m < 10; m++)
                    s_hred[m*256 + tid] += s_hred[m*256 + tid + sft];
            }
            __syncthreads();
        }
        if (tid < 10) out[bh*10 + tid] = s_hred[tid*256] + bl[tid];
        __syncthreads();
    }
}

// ---------------- host ----------------
extern "C" void kernel_launch(void* const* d_in, const int* in_sizes, int n_in,
                              void* d_out, int out_size, void* d_ws, size_t ws_size,
                              hipStream_t stream)
{
    const float* x  = (const float*)d_in[0];
    const float* w1 = (const float*)d_in[1];
    const float* b1 = (const float*)d_in[2];
    const float* w2 = (const float*)d_in[3];
    const float* b2 = (const float*)d_in[4];
    const float* w3 = (const float*)d_in[5];
    const float* b3 = (const float*)d_in[6];
    const float* wl = (const float*)d_in[7];
    const float* bl = (const float*)d_in[8];
    float* out = (float*)d_out;

    float* F = (float*)d_ws;
    float* part = F + OFF_PART;
    int*   flags = (int*)(F + OFF_FLAG);
    float* tsum = F + OFF_TSUM;
    _Float16* w2p = (_Float16*)(F + OFF_W2P);
    float* y    = F + OFF_Y;
    float* y5   = F + OFF_Y5;
    float* kbp  = F + OFF_K;
    float* wpk  = F + OFF_WPK;
    int*   flagT = (int*)(F + OFF_FT);
    int*   flagB = (int*)(F + OFF_FB);

    k_init<<<NS/256, 256, 0, stream>>>(x, y, flags, flagT, flagB);
    k_prepack<<<144, 256, 0, stream>>>(w1, w2, w3, w2p, tsum, wpk);

    int maxb = 0;
    if (hipOccupancyMaxActiveBlocksPerMultiprocessor(&maxb,
            reinterpret_cast<const void*>(k_ode), 256, 0) != hipSuccess || maxb < 1)
        maxb = 1;
    int cus = 256;
    {
        int dev = 0;
        hipGetDevice(&dev);
        hipDeviceProp_t prop;
        if (hipGetDeviceProperties(&prop, dev) == hipSuccess && prop.multiProcessorCount > 0)
            cus = prop.multiProcessorCount;
    }
    long cap = (long)maxb * (long)cus;
    int gridn = (int)((cap < 512) ? cap : 512);
    if (gridn < 16) gridn = 16;

    k_ode<<<gridn, 256, 0, stream>>>(b1, b2, b3, w2p, tsum, wpk, wl, bl,
                                     y, y5, kbp, part, flags, flagT, flagB, out);
}